// Round 14
// baseline (210.027 us; speedup 1.0000x reference)
//
#include <hip/hip_runtime.h>

#define N_NODES 100000
#define F_IN    128
#define H_DIM   64
#define C_DIM   16
#define NBKT    391            // ceil(100000 / 256) buckets of 256 nodes (dst>>8)
#define BKT_PAD 16             // one bucket counter per 64B line
#define CHUNK   4096           // edges per block in bucket phases
#define CAP     8960           // padded bucket capacity (lambda=8192, +8.5 sigma)

__device__ __forceinline__ void fma4(float4& acc, float s, const float4& w) {
    acc.x = fmaf(s, w.x, acc.x);
    acc.y = fmaf(s, w.y, acc.y);
    acc.z = fmaf(s, w.z, acc.z);
    acc.w = fmaf(s, w.w, acc.w);
}
// f32 -> bf16 round-to-nearest-even
__device__ __forceinline__ unsigned bfr(float f) {
    unsigned u = __float_as_uint(f);
    return (u + (((u >> 16) & 1u) + 0x7FFFu)) >> 16;
}
// unpack-add: two packed bf16 pairs -> 4 f32 adds
__device__ __forceinline__ void accb(float4& a, uint2 u) {
    a.x += __uint_as_float(u.x << 16);
    a.y += __uint_as_float(u.x & 0xFFFF0000u);
    a.z += __uint_as_float(u.y << 16);
    a.w += __uint_as_float(u.y & 0xFFFF0000u);
}

// ---------- CSR build ----------
__global__ void k_zero_b(int* __restrict__ b) {
    int i = blockIdx.x * blockDim.x + threadIdx.x;
    if (i < NBKT * BKT_PAD) b[i] = 0;
}

// single pass: LDS hist (rank captured from atomic return) -> reserve bucket
// range -> bucket-grouped write. pairs packed: (src<<8) | (dst & 255)
__global__ __launch_bounds__(256) void k_bfill(const int2* __restrict__ edges,
                                               int* __restrict__ bkt_tail,
                                               int* __restrict__ pairs, int E) {
    __shared__ int cnt[NBKT];
    __shared__ int row[NBKT];
    for (int t = threadIdx.x; t < NBKT; t += 256) cnt[t] = 0;
    __syncthreads();
    int base = blockIdx.x * CHUNK;
    int2 ed[CHUNK / 256];                   // 16 int2 in registers (static idx via unroll)
    int  rk[CHUNK / 256];                   // local rank within (block, bucket)
    #pragma unroll
    for (int i = 0; i < CHUNK / 256; ++i) {
        int e = base + i * 256 + threadIdx.x;
        if (e < E) {
            ed[i] = edges[e];
            rk[i] = atomicAdd(&cnt[ed[i].y >> 8], 1);   // rank = pre-increment value
        }
    }
    __syncthreads();
    for (int t = threadIdx.x; t < NBKT; t += 256)
        row[t] = cnt[t] ? atomicAdd(&bkt_tail[t * BKT_PAD], cnt[t]) : 0;
    __syncthreads();
    #pragma unroll
    for (int i = 0; i < CHUNK / 256; ++i) {
        int e = base + i * 256 + threadIdx.x;
        if (e < E) {
            int bkt = ed[i].y >> 8;
            int pos = row[bkt] + rk[i];                 // no second atomic pass
            if (pos < CAP) pairs[bkt * CAP + pos] = (ed[i].x << 8) | (ed[i].y & 255);
        }
    }
}

// one block per bucket, 1024 threads (16 waves: grid is only 391 blocks = 1.5/CU,
// so big blocks are the only way to get waves on-CU for latency hiding).
__global__ __launch_bounds__(1024) void k_bnode(const int* __restrict__ pairs,
                                                const int* __restrict__ bkt_tail,
                                                int* __restrict__ csr_src,
                                                int* __restrict__ node_base,
                                                int* __restrict__ node_cnt,
                                                float* __restrict__ dinv) {
    __shared__ int sc[CAP];                 // 35 KB staged csr (src ids by local pos)
    __shared__ int cnt[256];
    __shared__ int row[256];
    __shared__ int wsum[4];
    int b = blockIdx.x;
    int t = threadIdx.x;
    if (t < 256) cnt[t] = 0;
    __syncthreads();
    int start = b * CAP;
    int m     = min(bkt_tail[b * BKT_PAD], CAP);
    for (int e = t; e < m; e += 1024)
        atomicAdd(&cnt[pairs[start + e] & 255], 1);     // pass 1 (L2-hot)
    __syncthreads();
    if (t < 256) {
        int c = cnt[t];
        // 256-wide exclusive scan: wave shfl scan + cross-wave combine
        int lane = t & 63, wv = t >> 6;
        int v = c;
        #pragma unroll
        for (int off = 1; off < 64; off <<= 1) {
            int u = __shfl_up(v, off);
            if (lane >= off) v += u;
        }
        if (lane == 63) wsum[wv] = v;
        __syncthreads();
        int woff = 0;
        #pragma unroll
        for (int w = 0; w < 4; ++w) woff += (w < wv) ? wsum[w] : 0;
        int incl = v + woff;                // inclusive over 256
        row[t] = incl - c;                  // local exclusive base
        int node = b * 256 + t;
        if (node < N_NODES) {
            node_base[node] = start + incl - c;
            node_cnt[node]  = c;
            dinv[node]      = rsqrtf((float)(c + 1));   // deg = cnt + 1 (self loop)
        }
    } else {
        __syncthreads();                    // match the scan's inner barrier
    }
    __syncthreads();
    for (int e = t; e < m; e += 1024) {
        int p   = pairs[start + e];                 // pass 2 (L2-hot)
        int pos = atomicAdd(&row[p & 255], 1);      // LDS atomic, local pos
        sc[pos] = ((unsigned)p) >> 8;
    }
    __syncthreads();
    for (int e = t; e < m; e += 1024)
        csr_src[start + e] = sc[e];                 // coalesced copy-out
}

// ---------- GEMM1 v3 (register-tiled, R=4): 64 rows/block, 4 rows x 4 cols/thread ----
__global__ __launch_bounds__(256) void k_gemm1(const float* __restrict__ x,
                                               const float* __restrict__ W1,
                                               const float* __restrict__ dinv,
                                               uint2* __restrict__ g1b) {
    __shared__ float4 wlds[F_IN * 16];               // [k][colq] 32 KB
    int tid = threadIdx.x;
    const float4* w4 = (const float4*)W1;
    #pragma unroll
    for (int i = 0; i < 8; ++i) wlds[tid + 256 * i] = w4[tid + 256 * i];
    __syncthreads();

    int colq = tid & 15;
    int rq   = tid >> 4;                             // 0..15
    int row0 = blockIdx.x * 64 + rq * 4;
    const float4* xb = (const float4*)x;             // row stride = 32 float4

    float4 a0 = {0.f,0.f,0.f,0.f}, a1 = a0, a2 = a0, a3 = a0;
    size_t x0 = (size_t)(row0 + 0 < N_NODES ? row0 + 0 : 0) * 32;
    size_t x1 = (size_t)(row0 + 1 < N_NODES ? row0 + 1 : 0) * 32;
    size_t x2 = (size_t)(row0 + 2 < N_NODES ? row0 + 2 : 0) * 32;
    size_t x3 = (size_t)(row0 + 3 < N_NODES ? row0 + 3 : 0) * 32;

    #pragma unroll 4
    for (int k4 = 0; k4 < F_IN / 4; ++k4) {
        float4 w0 = wlds[(4 * k4 + 0) * 16 + colq];  // 4 LDS reads serve 64 fmas
        float4 w1 = wlds[(4 * k4 + 1) * 16 + colq];
        float4 w2 = wlds[(4 * k4 + 2) * 16 + colq];
        float4 w3 = wlds[(4 * k4 + 3) * 16 + colq];
        float4 v0 = xb[x0 + k4];                     // 4 independent broadcast loads
        float4 v1 = xb[x1 + k4];
        float4 v2 = xb[x2 + k4];
        float4 v3 = xb[x3 + k4];
        fma4(a0, v0.x, w0); fma4(a0, v0.y, w1); fma4(a0, v0.z, w2); fma4(a0, v0.w, w3);
        fma4(a1, v1.x, w0); fma4(a1, v1.y, w1); fma4(a1, v1.z, w2); fma4(a1, v1.w, w3);
        fma4(a2, v2.x, w0); fma4(a2, v2.y, w1); fma4(a2, v2.z, w2); fma4(a2, v2.w, w3);
        fma4(a3, v3.x, w0); fma4(a3, v3.y, w1); fma4(a3, v3.z, w2); fma4(a3, v3.w, w3);
    }
    #pragma unroll
    for (int j = 0; j < 4; ++j) {
        int r = row0 + j;
        if (r < N_NODES) {
            float4 aj = (j == 0) ? a0 : (j == 1) ? a1 : (j == 2) ? a2 : a3;
            float di = dinv[r];
            uint2 p;
            p.x = bfr(aj.x * di) | (bfr(aj.y * di) << 16);
            p.y = bfr(aj.z * di) | (bfr(aj.w * di) << 16);
            g1b[(size_t)r * 16 + colq] = p;
        }
    }
}

// ---------- fused gather1 + bias + relu + GEMM2 (node range from node0) ----------
__global__ __launch_bounds__(256) void k_gather1(const int* __restrict__ csr_src,
                                                 const int* __restrict__ base,
                                                 const int* __restrict__ cnt,
                                                 const float* __restrict__ dinv,
                                                 const uint2* __restrict__ g1b,  // [N][16]
                                                 const float* __restrict__ b1,
                                                 const float* __restrict__ W2,   // [64][16]
                                                 uint2* __restrict__ g2b,        // [N][4]
                                                 int node0) {
    __shared__ float  w2t[16 * 68];          // W2^T, rows padded to 68 floats
    __shared__ float4 ysh[4][68];            // per-wave y staging, 17-f4 group stride
    int tid = threadIdx.x;
    #pragma unroll
    for (int i = 0; i < 4; ++i) {
        int idx = i * 256 + tid;             // idx = f*16 + j
        w2t[(idx & 15) * 68 + (idx >> 4)] = W2[idx];
    }
    __syncthreads();

    int lane = tid & 63;
    int wv   = tid >> 6;                     // wave in block
    int grp  = lane >> 4;                    // 0..3
    int l16  = lane & 15;
    int g0   = lane & 48;                    // group base lane (absolute in wave)
    int node = node0 + ((blockIdx.x * 256 + tid) >> 6) * 4 + grp;
    int   b  = base[node];
    int   c  = cnt[node];
    float di = dinv[node];
    float4 acc = {0.f, 0.f, 0.f, 0.f};
    accb(acc, g1b[(size_t)node * 16 + l16]);           // self term

    for (int k0 = 0; k0 < c; k0 += 16) {
        int k = k0 + l16;
        int sidx = (k < c) ? csr_src[b + k] : 0;       // group-coalesced stage
        int nj = min(16, c - k0);
        int j = 0;
        for (; j + 4 <= nj; j += 4) {
            int s0 = __shfl(sidx, g0 + j + 0);
            int s1 = __shfl(sidx, g0 + j + 1);
            int s2 = __shfl(sidx, g0 + j + 2);
            int s3 = __shfl(sidx, g0 + j + 3);
            uint2 u0 = g1b[(size_t)s0 * 16 + l16];     // 4 independent 128B rows
            uint2 u1 = g1b[(size_t)s1 * 16 + l16];
            uint2 u2 = g1b[(size_t)s2 * 16 + l16];
            uint2 u3 = g1b[(size_t)s3 * 16 + l16];
            accb(acc, u0); accb(acc, u1); accb(acc, u2); accb(acc, u3);
        }
        for (; j < nj; ++j) {
            accb(acc, g1b[(size_t)__shfl(sidx, g0 + j) * 16 + l16]);
        }
    }

    // epilogue: y = di*relu(b1 + di*acc), transpose via LDS, y @ W2 -> g2b
    float4 bv = ((const float4*)b1)[l16];
    float4 y;
    y.x = fmaxf(fmaf(di, acc.x, bv.x), 0.f) * di;
    y.y = fmaxf(fmaf(di, acc.y, bv.y), 0.f) * di;
    y.z = fmaxf(fmaf(di, acc.z, bv.z), 0.f) * di;
    y.w = fmaxf(fmaf(di, acc.w, bv.w), 0.f) * di;
    ysh[wv][grp * 17 + l16] = y;             // wave-internal, DS-pipe ordered

    float o = 0.f;                           // this lane's output column j = l16
    #pragma unroll
    for (int f4 = 0; f4 < 16; ++f4) {
        float4 yv = ysh[wv][grp * 17 + f4];            // broadcast within group
        const float4* wr = (const float4*)&w2t[l16 * 68 + f4 * 4];
        float4 wv4 = *wr;
        o = fmaf(yv.x, wv4.x, o);
        o = fmaf(yv.y, wv4.y, o);
        o = fmaf(yv.z, wv4.z, o);
        o = fmaf(yv.w, wv4.w, o);
    }
    float o1 = __shfl_down(o, 1);
    float o2 = __shfl_down(o, 2);
    float o3 = __shfl_down(o, 3);
    if ((l16 & 3) == 0) {
        uint2 pk;
        pk.x = bfr(o)  | (bfr(o1) << 16);
        pk.y = bfr(o2) | (bfr(o3) << 16);
        g2b[(size_t)node * 4 + (l16 >> 2)] = pk;
    }
}

// ---------- gather layer 2: 4-lane group per node (16 nodes/wave), bf16 rows ----------
__global__ __launch_bounds__(256) void k_gather2(const int* __restrict__ csr_src,
                                                 const int* __restrict__ base,
                                                 const int* __restrict__ cnt,
                                                 const float* __restrict__ dinv,
                                                 const uint2* __restrict__ g2b,   // [N][4]
                                                 const float* __restrict__ b2,
                                                 float* __restrict__ out) {
    int tid  = threadIdx.x;
    int lane = tid & 63;
    int grp  = lane >> 2;                    // 0..15
    int l4   = lane & 3;
    int g0   = lane & 60;                    // group base lane
    int node = ((blockIdx.x * 256 + tid) >> 6) * 16 + grp;
    if (node >= N_NODES) return;
    int   b  = base[node];
    int   c  = cnt[node];
    float di = dinv[node];
    float4 acc = {0.f, 0.f, 0.f, 0.f};
    accb(acc, g2b[(size_t)node * 4 + l4]);             // self term

    for (int k0 = 0; k0 < c; k0 += 4) {
        int k = k0 + l4;
        int sidx = (k < c) ? csr_src[b + k] : 0;
        int nj = min(4, c - k0);
        if (nj == 4) {
            int s0 = __shfl(sidx, g0 + 0);
            int s1 = __shfl(sidx, g0 + 1);
            int s2 = __shfl(sidx, g0 + 2);
            int s3 = __shfl(sidx, g0 + 3);
            uint2 u0 = g2b[(size_t)s0 * 4 + l4];       // 4 independent 32B rows
            uint2 u1 = g2b[(size_t)s1 * 4 + l4];
            uint2 u2 = g2b[(size_t)s2 * 4 + l4];
            uint2 u3 = g2b[(size_t)s3 * 4 + l4];
            accb(acc, u0); accb(acc, u1); accb(acc, u2); accb(acc, u3);
        } else {
            for (int j = 0; j < nj; ++j)
                accb(acc, g2b[(size_t)__shfl(sidx, g0 + j) * 4 + l4]);
        }
    }
    float4 bv = ((const float4*)b2)[l4];
    float4 r  = { fmaf(di, acc.x, bv.x), fmaf(di, acc.y, bv.y),
                  fmaf(di, acc.z, bv.z), fmaf(di, acc.w, bv.w) };
    ((float4*)out)[(size_t)node * 4 + l4] = r;
}

extern "C" void kernel_launch(void* const* d_in, const int* in_sizes, int n_in,
                              void* d_out, int out_size, void* d_ws, size_t ws_size,
                              hipStream_t stream) {
    const float* x     = (const float*)d_in[0];
    const int*   edges = (const int*)d_in[1];              // int32 (harness converts)
    const float* W1    = (const float*)d_in[2];
    const float* b1    = (const float*)d_in[3];
    const float* W2    = (const float*)d_in[4];
    const float* b2    = (const float*)d_in[5];
    float*       out   = (float*)d_out;

    const int E = in_sizes[1] / 2;                         // 3,200,000

    // workspace (~32.8 MB), concurrently-live regions disjoint:
    //   [0, 14.0 MB):    pairs (build)  -> g1b (bf16 12.8 MB; live through gather1)
    //   [14.0, 17.2 MB): g2b (bf16, N*4 uint2 = 3.2 MB; written by gather1)
    //   [17.2, 31.2 MB): csr_src (NBKT*CAP ints)
    //   [31.2, ...):     nbase | ncnt | dinv | bkt_tail
    int*   pairs   = (int*)d_ws;                           // NBKT*CAP ints
    uint2* g1b     = (uint2*)d_ws;                         // N*16 uint2 (bf16 rows)
    uint2* g2b     = (uint2*)((float*)d_ws + (size_t)NBKT * CAP);
    int*   csr_src = (int*)g2b + (size_t)N_NODES * 8 + 64; // after g2b (N*4 uint2 = N*8 int)
    int*   nbase   = csr_src + (size_t)NBKT * CAP;         // N
    int*   ncnt    = nbase + N_NODES;                      // N
    float* dinv    = (float*)(ncnt + N_NODES);             // N
    int*   bkt_tail= (int*)(dinv + N_NODES);               // NBKT*16

    const int nchunk = (E + CHUNK - 1) / CHUNK;            // 782

    // CSR build (single-pass padded-bucket sort by dst)
    k_zero_b <<<(NBKT * BKT_PAD + 255) / 256, 256, 0, stream>>>(bkt_tail);
    k_bfill  <<<nchunk, 256, 0, stream>>>((const int2*)edges, bkt_tail, pairs, E);
    k_bnode  <<<NBKT, 1024, 0, stream>>>(pairs, bkt_tail, csr_src, nbase, ncnt, dinv);

    // layer 1 GEMM (register-tiled R=4, dinv-prescaled bf16 rows)
    k_gemm1   <<<(N_NODES + 63) / 64, 256, 0, stream>>>(x, W1, dinv, g1b);

    // fused: gather1 + bias + relu + GEMM2 -> g2b.
    // Split x3 (diagnostic): keeps gather1 thirds (~19 us) below the unprofiled
    // kernels so top-5 reveals the true runner-up next round.
    k_gather1 <<<2084, 256, 0, stream>>>(csr_src, nbase, ncnt, dinv, g1b, b1, W2, g2b, 0);
    k_gather1 <<<2083, 256, 0, stream>>>(csr_src, nbase, ncnt, dinv, g1b, b1, W2, g2b, 33344);
    k_gather1 <<<2083, 256, 0, stream>>>(csr_src, nbase, ncnt, dinv, g1b, b1, W2, g2b, 66672);

    // gather layer 2 -> out
    k_gather2 <<<1563, 256, 0, stream>>>(csr_src, nbase, ncnt, dinv, g2b, b2, out);
}

// Round 15
// 209.015 us; speedup vs baseline: 1.0048x; 1.0048x over previous
//
#include <hip/hip_runtime.h>

#define N_NODES 100000
#define F_IN    128
#define H_DIM   64
#define C_DIM   16
#define NBKT_W  98             // wide buckets (1024 nodes) for bfill writes
#define NBKT_S  391            // sub-buckets (256 nodes) = bnode blocks
#define BKT_PAD 16             // one counter per 64B line
#define CHUNK   4096           // edges per block in bfill
#define CAP_W   34816          // per-wide-bucket capacity (lambda=32768, +11 sigma)
#define CAP_SUB 8960           // per-sub-bucket capacity (lambda=8192, +8.5 sigma)

__device__ __forceinline__ void fma4(float4& acc, float s, const float4& w) {
    acc.x = fmaf(s, w.x, acc.x);
    acc.y = fmaf(s, w.y, acc.y);
    acc.z = fmaf(s, w.z, acc.z);
    acc.w = fmaf(s, w.w, acc.w);
}
// f32 -> bf16 round-to-nearest-even
__device__ __forceinline__ unsigned bfr(float f) {
    unsigned u = __float_as_uint(f);
    return (u + (((u >> 16) & 1u) + 0x7FFFu)) >> 16;
}
// unpack-add: two packed bf16 pairs -> 4 f32 adds
__device__ __forceinline__ void accb(float4& a, uint2 u) {
    a.x += __uint_as_float(u.x << 16);
    a.y += __uint_as_float(u.x & 0xFFFF0000u);
    a.z += __uint_as_float(u.y << 16);
    a.w += __uint_as_float(u.y & 0xFFFF0000u);
}

// ---------- CSR build ----------
__global__ void k_zero_b(int* __restrict__ b, int n) {
    int i = blockIdx.x * blockDim.x + threadIdx.x;
    if (i < n) b[i] = 0;
}

// single pass over edges: wide-bucket LDS hist with rank capture + sub-bucket
// counts -> reserve wide range -> bucket-grouped write of packed pairs.
// pairs packed: (src<<10) | (dst & 1023); wide bucket = dst>>10.
__global__ __launch_bounds__(512) void k_bfill(const int2* __restrict__ edges,
                                               int* __restrict__ bkt_tail,
                                               int* __restrict__ sub_tot,
                                               int* __restrict__ pairs, int E) {
    __shared__ int cntw[NBKT_W];
    __shared__ int roww[NBKT_W];
    __shared__ int cnts[NBKT_S + 1];
    int t = threadIdx.x;
    for (int i = t; i < NBKT_W; i += 512) cntw[i] = 0;
    for (int i = t; i < NBKT_S + 1; i += 512) cnts[i] = 0;
    __syncthreads();
    int base = blockIdx.x * CHUNK;
    int2 ed[8];                              // 8 edges/thread (static idx via unroll)
    int  rk[8];                              // rank within (block, wide bucket)
    #pragma unroll
    for (int i = 0; i < 8; ++i) {
        int e = base + i * 512 + t;
        if (e < E) {
            ed[i] = edges[e];
            rk[i] = atomicAdd(&cntw[ed[i].y >> 10], 1);
            atomicAdd(&cnts[ed[i].y >> 8], 1);
        }
    }
    __syncthreads();
    for (int i = t; i < NBKT_W; i += 512)
        roww[i] = cntw[i] ? atomicAdd(&bkt_tail[i * BKT_PAD], cntw[i]) : 0;
    for (int i = t; i < NBKT_S + 1; i += 512)
        if (cnts[i]) atomicAdd(&sub_tot[i * BKT_PAD], cnts[i]);
    __syncthreads();
    #pragma unroll
    for (int i = 0; i < 8; ++i) {
        int e = base + i * 512 + t;
        if (e < E) {
            int wb  = ed[i].y >> 10;
            int pos = roww[wb] + rk[i];
            if (pos < CAP_W) pairs[wb * CAP_W + pos] = (ed[i].x << 10) | (ed[i].y & 1023);
        }
    }
}

// one block per 256-node sub-bucket: scan parent wide bucket (L2-hot), filter own
// quarter, LDS scatter to node order, coalesced copy-out. base/cnt/dinv outputs.
__global__ __launch_bounds__(1024) void k_bnode(const int* __restrict__ pairs,
                                                const int* __restrict__ bkt_tail,
                                                const int* __restrict__ sub_tot,
                                                int* __restrict__ csr_src,
                                                int* __restrict__ node_base,
                                                int* __restrict__ node_cnt,
                                                float* __restrict__ dinv) {
    __shared__ int sc[CAP_SUB];              // 35 KB staged csr (src ids, local pos)
    __shared__ int cnt[256];
    __shared__ int row[256];
    __shared__ int wsum[4];
    __shared__ int sb_sh;
    int s = blockIdx.x;                      // sub-bucket id 0..390
    int w = s >> 2, sub = s & 3;
    int t = threadIdx.x;
    if (t < 256) cnt[t] = 0;
    __syncthreads();
    int start = w * CAP_W;
    int m     = min(bkt_tail[w * BKT_PAD], CAP_W);
    for (int e = t; e < m; e += 1024) {
        int p = pairs[start + e];            // pass 1: hist own sub only
        if (((p >> 8) & 3) == sub) atomicAdd(&cnt[p & 255], 1);
    }
    if (t == 0) {                            // sub offset within parent region
        int sb = start;
        for (int u = 0; u < sub; ++u) sb += sub_tot[(w * 4 + u) * BKT_PAD];
        sb_sh = sb;
    }
    __syncthreads();
    int sb = sb_sh;
    int c = 0, incl = 0;
    if (t < 256) {                           // wave-shfl scan (no barrier inside)
        c = cnt[t];
        int lane = t & 63, wv = t >> 6;
        int v = c;
        #pragma unroll
        for (int off = 1; off < 64; off <<= 1) {
            int u = __shfl_up(v, off);
            if (lane >= off) v += u;
        }
        if (lane == 63) wsum[wv] = v;
        incl = v;
    }
    __syncthreads();
    if (t < 256) {
        int wv = t >> 6;
        int woff = 0;
        #pragma unroll
        for (int u = 0; u < 4; ++u) woff += (u < wv) ? wsum[u] : 0;
        incl += woff;                        // inclusive over 256
        row[t] = incl - c;                   // local exclusive base (0-based)
        int node = s * 256 + t;
        if (node < N_NODES) {
            node_base[node] = sb + incl - c;
            node_cnt[node]  = c;
            dinv[node]      = rsqrtf((float)(c + 1));  // deg = cnt + 1 (self loop)
        }
    }
    __syncthreads();
    int ts = wsum[0] + wsum[1] + wsum[2] + wsum[3];
    for (int e = t; e < m; e += 1024) {
        int p = pairs[start + e];            // pass 2
        if (((p >> 8) & 3) == sub) {
            int pos = atomicAdd(&row[p & 255], 1);     // LDS atomic, local pos
            if (pos < CAP_SUB) sc[pos] = ((unsigned)p) >> 10;
        }
    }
    __syncthreads();
    int lim = min(ts, CAP_SUB);
    for (int e = t; e < lim; e += 1024)
        csr_src[sb + e] = sc[e];             // coalesced copy-out
}

// ---------- GEMM1 (R=4, 512 threads): 128 rows/block, 4 rows x 4 cols/thread ----
// 512-thread blocks: 8 waves share the 32KB LDS -> wave cap 32/CU (vs 20 at 256thr)
__global__ __launch_bounds__(512) void k_gemm1(const float* __restrict__ x,
                                               const float* __restrict__ W1,
                                               const float* __restrict__ dinv,
                                               uint2* __restrict__ g1b) {
    __shared__ float4 wlds[F_IN * 16];               // [k][colq] 32 KB
    int tid = threadIdx.x;
    const float4* w4 = (const float4*)W1;
    #pragma unroll
    for (int i = 0; i < 4; ++i) wlds[tid + 512 * i] = w4[tid + 512 * i];
    __syncthreads();

    int colq = tid & 15;
    int rq   = tid >> 4;                             // 0..31
    int row0 = blockIdx.x * 128 + rq * 4;
    const float4* xb = (const float4*)x;             // row stride = 32 float4

    float4 a0 = {0.f,0.f,0.f,0.f}, a1 = a0, a2 = a0, a3 = a0;
    size_t x0 = (size_t)(row0 + 0 < N_NODES ? row0 + 0 : 0) * 32;
    size_t x1 = (size_t)(row0 + 1 < N_NODES ? row0 + 1 : 0) * 32;
    size_t x2 = (size_t)(row0 + 2 < N_NODES ? row0 + 2 : 0) * 32;
    size_t x3 = (size_t)(row0 + 3 < N_NODES ? row0 + 3 : 0) * 32;

    #pragma unroll 4
    for (int k4 = 0; k4 < F_IN / 4; ++k4) {
        float4 w0 = wlds[(4 * k4 + 0) * 16 + colq];  // 4 LDS reads serve 64 fmas
        float4 w1 = wlds[(4 * k4 + 1) * 16 + colq];
        float4 w2 = wlds[(4 * k4 + 2) * 16 + colq];
        float4 w3 = wlds[(4 * k4 + 3) * 16 + colq];
        float4 v0 = xb[x0 + k4];                     // 4 independent broadcast loads
        float4 v1 = xb[x1 + k4];
        float4 v2 = xb[x2 + k4];
        float4 v3 = xb[x3 + k4];
        fma4(a0, v0.x, w0); fma4(a0, v0.y, w1); fma4(a0, v0.z, w2); fma4(a0, v0.w, w3);
        fma4(a1, v1.x, w0); fma4(a1, v1.y, w1); fma4(a1, v1.z, w2); fma4(a1, v1.w, w3);
        fma4(a2, v2.x, w0); fma4(a2, v2.y, w1); fma4(a2, v2.z, w2); fma4(a2, v2.w, w3);
        fma4(a3, v3.x, w0); fma4(a3, v3.y, w1); fma4(a3, v3.z, w2); fma4(a3, v3.w, w3);
    }
    #pragma unroll
    for (int j = 0; j < 4; ++j) {
        int r = row0 + j;
        if (r < N_NODES) {
            float4 aj = (j == 0) ? a0 : (j == 1) ? a1 : (j == 2) ? a2 : a3;
            float di = dinv[r];
            uint2 p;
            p.x = bfr(aj.x * di) | (bfr(aj.y * di) << 16);
            p.y = bfr(aj.z * di) | (bfr(aj.w * di) << 16);
            g1b[(size_t)r * 16 + colq] = p;
        }
    }
}

// ---------- fused gather1 + bias + relu + GEMM2 ----------
__global__ __launch_bounds__(256) void k_gather1(const int* __restrict__ csr_src,
                                                 const int* __restrict__ base,
                                                 const int* __restrict__ cnt,
                                                 const float* __restrict__ dinv,
                                                 const uint2* __restrict__ g1b,  // [N][16]
                                                 const float* __restrict__ b1,
                                                 const float* __restrict__ W2,   // [64][16]
                                                 uint2* __restrict__ g2b) {      // [N][4]
    __shared__ float  w2t[16 * 68];          // W2^T, rows padded to 68 floats
    __shared__ float4 ysh[4][68];            // per-wave y staging, 17-f4 group stride
    int tid = threadIdx.x;
    #pragma unroll
    for (int i = 0; i < 4; ++i) {
        int idx = i * 256 + tid;             // idx = f*16 + j
        w2t[(idx & 15) * 68 + (idx >> 4)] = W2[idx];
    }
    __syncthreads();

    int lane = tid & 63;
    int wv   = tid >> 6;                     // wave in block
    int grp  = lane >> 4;                    // 0..3
    int l16  = lane & 15;
    int g0   = lane & 48;                    // group base lane (absolute in wave)
    int node = ((blockIdx.x * 256 + tid) >> 6) * 4 + grp;   // exact: 25000 waves * 4
    int   b  = base[node];
    int   c  = cnt[node];
    float di = dinv[node];
    float4 acc = {0.f, 0.f, 0.f, 0.f};
    accb(acc, g1b[(size_t)node * 16 + l16]);           // self term

    for (int k0 = 0; k0 < c; k0 += 16) {
        int k = k0 + l16;
        int sidx = (k < c) ? csr_src[b + k] : 0;       // group-coalesced stage
        int nj = min(16, c - k0);
        int j = 0;
        for (; j + 4 <= nj; j += 4) {
            int s0 = __shfl(sidx, g0 + j + 0);
            int s1 = __shfl(sidx, g0 + j + 1);
            int s2 = __shfl(sidx, g0 + j + 2);
            int s3 = __shfl(sidx, g0 + j + 3);
            uint2 u0 = g1b[(size_t)s0 * 16 + l16];     // 4 independent 128B rows
            uint2 u1 = g1b[(size_t)s1 * 16 + l16];
            uint2 u2 = g1b[(size_t)s2 * 16 + l16];
            uint2 u3 = g1b[(size_t)s3 * 16 + l16];
            accb(acc, u0); accb(acc, u1); accb(acc, u2); accb(acc, u3);
        }
        for (; j < nj; ++j) {
            accb(acc, g1b[(size_t)__shfl(sidx, g0 + j) * 16 + l16]);
        }
    }

    // epilogue: y = di*relu(b1 + di*acc), transpose via LDS, y @ W2 -> g2b
    float4 bv = ((const float4*)b1)[l16];
    float4 y;
    y.x = fmaxf(fmaf(di, acc.x, bv.x), 0.f) * di;
    y.y = fmaxf(fmaf(di, acc.y, bv.y), 0.f) * di;
    y.z = fmaxf(fmaf(di, acc.z, bv.z), 0.f) * di;
    y.w = fmaxf(fmaf(di, acc.w, bv.w), 0.f) * di;
    ysh[wv][grp * 17 + l16] = y;             // wave-internal, DS-pipe ordered

    float o = 0.f;                           // this lane's output column j = l16
    #pragma unroll
    for (int f4 = 0; f4 < 16; ++f4) {
        float4 yv = ysh[wv][grp * 17 + f4];            // broadcast within group
        const float4* wr = (const float4*)&w2t[l16 * 68 + f4 * 4];
        float4 wv4 = *wr;
        o = fmaf(yv.x, wv4.x, o);
        o = fmaf(yv.y, wv4.y, o);
        o = fmaf(yv.z, wv4.z, o);
        o = fmaf(yv.w, wv4.w, o);
    }
    float o1 = __shfl_down(o, 1);
    float o2 = __shfl_down(o, 2);
    float o3 = __shfl_down(o, 3);
    if ((l16 & 3) == 0) {
        uint2 pk;
        pk.x = bfr(o)  | (bfr(o1) << 16);
        pk.y = bfr(o2) | (bfr(o3) << 16);
        g2b[(size_t)node * 4 + (l16 >> 2)] = pk;
    }
}

// ---------- gather layer 2: 4-lane group per node (16 nodes/wave), bf16 rows ----------
__global__ __launch_bounds__(256) void k_gather2(const int* __restrict__ csr_src,
                                                 const int* __restrict__ base,
                                                 const int* __restrict__ cnt,
                                                 const float* __restrict__ dinv,
                                                 const uint2* __restrict__ g2b,   // [N][4]
                                                 const float* __restrict__ b2,
                                                 float* __restrict__ out) {
    int tid  = threadIdx.x;
    int lane = tid & 63;
    int grp  = lane >> 2;                    // 0..15
    int l4   = lane & 3;
    int g0   = lane & 60;                    // group base lane
    int node = ((blockIdx.x * 256 + tid) >> 6) * 16 + grp;
    if (node >= N_NODES) return;
    int   b  = base[node];
    int   c  = cnt[node];
    float di = dinv[node];
    float4 acc = {0.f, 0.f, 0.f, 0.f};
    accb(acc, g2b[(size_t)node * 4 + l4]);             // self term

    for (int k0 = 0; k0 < c; k0 += 4) {
        int k = k0 + l4;
        int sidx = (k < c) ? csr_src[b + k] : 0;
        int nj = min(4, c - k0);
        if (nj == 4) {
            int s0 = __shfl(sidx, g0 + 0);
            int s1 = __shfl(sidx, g0 + 1);
            int s2 = __shfl(sidx, g0 + 2);
            int s3 = __shfl(sidx, g0 + 3);
            uint2 u0 = g2b[(size_t)s0 * 4 + l4];       // 4 independent 32B rows
            uint2 u1 = g2b[(size_t)s1 * 4 + l4];
            uint2 u2 = g2b[(size_t)s2 * 4 + l4];
            uint2 u3 = g2b[(size_t)s3 * 4 + l4];
            accb(acc, u0); accb(acc, u1); accb(acc, u2); accb(acc, u3);
        } else {
            for (int j = 0; j < nj; ++j)
                accb(acc, g2b[(size_t)__shfl(sidx, g0 + j) * 4 + l4]);
        }
    }
    float4 bv = ((const float4*)b2)[l4];
    float4 r  = { fmaf(di, acc.x, bv.x), fmaf(di, acc.y, bv.y),
                  fmaf(di, acc.z, bv.z), fmaf(di, acc.w, bv.w) };
    ((float4*)out)[(size_t)node * 4 + l4] = r;
}

extern "C" void kernel_launch(void* const* d_in, const int* in_sizes, int n_in,
                              void* d_out, int out_size, void* d_ws, size_t ws_size,
                              hipStream_t stream) {
    const float* x     = (const float*)d_in[0];
    const int*   edges = (const int*)d_in[1];              // int32 (harness converts)
    const float* W1    = (const float*)d_in[2];
    const float* b1    = (const float*)d_in[3];
    const float* W2    = (const float*)d_in[4];
    const float* b2    = (const float*)d_in[5];
    float*       out   = (float*)d_out;

    const int E = in_sizes[1] / 2;                         // 3,200,000

    // workspace (~31.7 MB), concurrently-live regions disjoint:
    //   [0, 13.65 MB):      pairs (build) -> g1b (bf16 12.8 MB)
    //   [13.65, 16.85 MB):  g2b (bf16, N*4 uint2)
    //   [16.85, 30.5 MB):   csr_src (NBKT_W*CAP_W ints, sub-packed in parent pads)
    //   [30.5, ...):        nbase | ncnt | dinv | bkt_tail+sub_tot
    int*   pairs   = (int*)d_ws;                           // NBKT_W*CAP_W ints
    uint2* g1b     = (uint2*)d_ws;                         // N*16 uint2 (bf16 rows)
    uint2* g2b     = (uint2*)((float*)d_ws + (size_t)NBKT_W * CAP_W);
    int*   csr_src = (int*)g2b + (size_t)N_NODES * 8 + 64;
    int*   nbase   = csr_src + (size_t)NBKT_W * CAP_W;     // N
    int*   ncnt    = nbase + N_NODES;                      // N
    float* dinv    = (float*)(ncnt + N_NODES);             // N
    int*   tails   = (int*)(dinv + N_NODES);               // (98+392)*16
    int*   bkt_tail= tails;
    int*   sub_tot = tails + NBKT_W * BKT_PAD;

    const int nchunk = (E + CHUNK - 1) / CHUNK;            // 782
    const int nzero  = (NBKT_W + NBKT_S + 1) * BKT_PAD;

    // CSR build: wide-bucket fill (dense writes) + per-sub-bucket node sort
    k_zero_b <<<(nzero + 255) / 256, 256, 0, stream>>>(tails, nzero);
    k_bfill  <<<nchunk, 512, 0, stream>>>((const int2*)edges, bkt_tail, sub_tot, pairs, E);
    k_bnode  <<<NBKT_S, 1024, 0, stream>>>(pairs, bkt_tail, sub_tot, csr_src,
                                           nbase, ncnt, dinv);

    // layer 1 GEMM (R=4, 512-thread blocks, dinv-prescaled bf16 rows)
    k_gemm1   <<<(N_NODES + 127) / 128, 512, 0, stream>>>(x, W1, dinv, g1b);

    // fused: gather1 + bias + relu + GEMM2 -> g2b
    k_gather1 <<<6250, 256, 0, stream>>>(csr_src, nbase, ncnt, dinv, g1b, b1, W2, g2b);

    // gather layer 2 -> out
    k_gather2 <<<1563, 256, 0, stream>>>(csr_src, nbase, ncnt, dinv, g2b, b2, out);
}

// Round 16
// 194.879 us; speedup vs baseline: 1.0777x; 1.0725x over previous
//
#include <hip/hip_runtime.h>

#define N_NODES 100000
#define F_IN    128
#define H_DIM   64
#define C_DIM   16
#define NBKT    391            // ceil(100000 / 256) buckets of 256 nodes (dst>>8)
#define BKT_PAD 16             // one bucket counter per 64B line
#define CHUNK   4096           // edges per block in bucket phases
#define CAP     8960           // padded bucket capacity (lambda=8192, +8.5 sigma)

__device__ __forceinline__ void fma4(float4& acc, float s, const float4& w) {
    acc.x = fmaf(s, w.x, acc.x);
    acc.y = fmaf(s, w.y, acc.y);
    acc.z = fmaf(s, w.z, acc.z);
    acc.w = fmaf(s, w.w, acc.w);
}
// f32 -> bf16 round-to-nearest-even
__device__ __forceinline__ unsigned bfr(float f) {
    unsigned u = __float_as_uint(f);
    return (u + (((u >> 16) & 1u) + 0x7FFFu)) >> 16;
}
// unpack-add: two packed bf16 pairs -> 4 f32 adds
__device__ __forceinline__ void accb(float4& a, uint2 u) {
    a.x += __uint_as_float(u.x << 16);
    a.y += __uint_as_float(u.x & 0xFFFF0000u);
    a.z += __uint_as_float(u.y << 16);
    a.w += __uint_as_float(u.y & 0xFFFF0000u);
}

// ---------- CSR build (R13 measured config) ----------
__global__ void k_zero_b(int* __restrict__ b) {
    int i = blockIdx.x * blockDim.x + threadIdx.x;
    if (i < NBKT * BKT_PAD) b[i] = 0;
}

// single pass: LDS hist (rank captured from atomic return) -> reserve bucket
// range -> bucket-grouped write. pairs packed: (src<<8) | (dst & 255)
__global__ __launch_bounds__(256) void k_bfill(const int2* __restrict__ edges,
                                               int* __restrict__ bkt_tail,
                                               int* __restrict__ pairs, int E) {
    __shared__ int cnt[NBKT];
    __shared__ int row[NBKT];
    for (int t = threadIdx.x; t < NBKT; t += 256) cnt[t] = 0;
    __syncthreads();
    int base = blockIdx.x * CHUNK;
    int2 ed[CHUNK / 256];                   // 16 int2 in registers (static idx via unroll)
    int  rk[CHUNK / 256];                   // local rank within (block, bucket)
    #pragma unroll
    for (int i = 0; i < CHUNK / 256; ++i) {
        int e = base + i * 256 + threadIdx.x;
        if (e < E) {
            ed[i] = edges[e];
            rk[i] = atomicAdd(&cnt[ed[i].y >> 8], 1);   // rank = pre-increment value
        }
    }
    __syncthreads();
    for (int t = threadIdx.x; t < NBKT; t += 256)
        row[t] = cnt[t] ? atomicAdd(&bkt_tail[t * BKT_PAD], cnt[t]) : 0;
    __syncthreads();
    #pragma unroll
    for (int i = 0; i < CHUNK / 256; ++i) {
        int e = base + i * 256 + threadIdx.x;
        if (e < E) {
            int bkt = ed[i].y >> 8;
            int pos = row[bkt] + rk[i];                 // no second atomic pass
            if (pos < CAP) pairs[bkt * CAP + pos] = (ed[i].x << 8) | (ed[i].y & 255);
        }
    }
}

// one block per bucket, 1024 threads (grid 391 = 1.5 blocks/CU; big blocks give
// the CU 16 waves for latency hiding). Measured ~11 us in R13 accounting.
__global__ __launch_bounds__(1024) void k_bnode(const int* __restrict__ pairs,
                                                const int* __restrict__ bkt_tail,
                                                int* __restrict__ csr_src,
                                                int* __restrict__ node_base,
                                                int* __restrict__ node_cnt,
                                                float* __restrict__ dinv) {
    __shared__ int sc[CAP];                 // 35 KB staged csr (src ids by local pos)
    __shared__ int cnt[256];
    __shared__ int row[256];
    __shared__ int wsum[4];
    int b = blockIdx.x;
    int t = threadIdx.x;
    if (t < 256) cnt[t] = 0;
    __syncthreads();
    int start = b * CAP;
    int m     = min(bkt_tail[b * BKT_PAD], CAP);
    for (int e = t; e < m; e += 1024)
        atomicAdd(&cnt[pairs[start + e] & 255], 1);     // pass 1 (L2-hot)
    __syncthreads();
    if (t < 256) {
        int c = cnt[t];
        // 256-wide exclusive scan: wave shfl scan + cross-wave combine
        int lane = t & 63, wv = t >> 6;
        int v = c;
        #pragma unroll
        for (int off = 1; off < 64; off <<= 1) {
            int u = __shfl_up(v, off);
            if (lane >= off) v += u;
        }
        if (lane == 63) wsum[wv] = v;
        __syncthreads();
        int woff = 0;
        #pragma unroll
        for (int w = 0; w < 4; ++w) woff += (w < wv) ? wsum[w] : 0;
        int incl = v + woff;                // inclusive over 256
        row[t] = incl - c;                  // local exclusive base
        int node = b * 256 + t;
        if (node < N_NODES) {
            node_base[node] = start + incl - c;
            node_cnt[node]  = c;
            dinv[node]      = rsqrtf((float)(c + 1));   // deg = cnt + 1 (self loop)
        }
    } else {
        __syncthreads();                    // match the scan's inner barrier
    }
    __syncthreads();
    for (int e = t; e < m; e += 1024) {
        int p   = pairs[start + e];                 // pass 2 (L2-hot)
        int pos = atomicAdd(&row[p & 255], 1);      // LDS atomic, local pos
        sc[pos] = ((unsigned)p) >> 8;
    }
    __syncthreads();
    for (int e = t; e < m; e += 1024)
        csr_src[start + e] = sc[e];                 // coalesced copy-out
}

// ---------- GEMM1 (R=4, 512 threads): 128 rows/block, 4 rows x 4 cols/thread ----
// A/B vs R13's 256thr (49 us, 9.4 waves/CU): 8 waves share 32KB LDS -> 4 blocks
// x 8 waves = 32 wave slots, ~24 resident. Only change vs R13 this round.
__global__ __launch_bounds__(512) void k_gemm1(const float* __restrict__ x,
                                               const float* __restrict__ W1,
                                               const float* __restrict__ dinv,
                                               uint2* __restrict__ g1b) {
    __shared__ float4 wlds[F_IN * 16];               // [k][colq] 32 KB
    int tid = threadIdx.x;
    const float4* w4 = (const float4*)W1;
    #pragma unroll
    for (int i = 0; i < 4; ++i) wlds[tid + 512 * i] = w4[tid + 512 * i];
    __syncthreads();

    int colq = tid & 15;
    int rq   = tid >> 4;                             // 0..31
    int row0 = blockIdx.x * 128 + rq * 4;
    const float4* xb = (const float4*)x;             // row stride = 32 float4

    float4 a0 = {0.f,0.f,0.f,0.f}, a1 = a0, a2 = a0, a3 = a0;
    size_t x0 = (size_t)(row0 + 0 < N_NODES ? row0 + 0 : 0) * 32;
    size_t x1 = (size_t)(row0 + 1 < N_NODES ? row0 + 1 : 0) * 32;
    size_t x2 = (size_t)(row0 + 2 < N_NODES ? row0 + 2 : 0) * 32;
    size_t x3 = (size_t)(row0 + 3 < N_NODES ? row0 + 3 : 0) * 32;

    #pragma unroll 4
    for (int k4 = 0; k4 < F_IN / 4; ++k4) {
        float4 w0 = wlds[(4 * k4 + 0) * 16 + colq];  // 4 LDS reads serve 64 fmas
        float4 w1 = wlds[(4 * k4 + 1) * 16 + colq];
        float4 w2 = wlds[(4 * k4 + 2) * 16 + colq];
        float4 w3 = wlds[(4 * k4 + 3) * 16 + colq];
        float4 v0 = xb[x0 + k4];                     // 4 independent broadcast loads
        float4 v1 = xb[x1 + k4];
        float4 v2 = xb[x2 + k4];
        float4 v3 = xb[x3 + k4];
        fma4(a0, v0.x, w0); fma4(a0, v0.y, w1); fma4(a0, v0.z, w2); fma4(a0, v0.w, w3);
        fma4(a1, v1.x, w0); fma4(a1, v1.y, w1); fma4(a1, v1.z, w2); fma4(a1, v1.w, w3);
        fma4(a2, v2.x, w0); fma4(a2, v2.y, w1); fma4(a2, v2.z, w2); fma4(a2, v2.w, w3);
        fma4(a3, v3.x, w0); fma4(a3, v3.y, w1); fma4(a3, v3.z, w2); fma4(a3, v3.w, w3);
    }
    #pragma unroll
    for (int j = 0; j < 4; ++j) {
        int r = row0 + j;
        if (r < N_NODES) {
            float4 aj = (j == 0) ? a0 : (j == 1) ? a1 : (j == 2) ? a2 : a3;
            float di = dinv[r];
            uint2 p;
            p.x = bfr(aj.x * di) | (bfr(aj.y * di) << 16);
            p.y = bfr(aj.z * di) | (bfr(aj.w * di) << 16);
            g1b[(size_t)r * 16 + colq] = p;
        }
    }
}

// ---------- fused gather1 + bias + relu + GEMM2 ----------
__global__ __launch_bounds__(256) void k_gather1(const int* __restrict__ csr_src,
                                                 const int* __restrict__ base,
                                                 const int* __restrict__ cnt,
                                                 const float* __restrict__ dinv,
                                                 const uint2* __restrict__ g1b,  // [N][16]
                                                 const float* __restrict__ b1,
                                                 const float* __restrict__ W2,   // [64][16]
                                                 uint2* __restrict__ g2b) {      // [N][4]
    __shared__ float  w2t[16 * 68];          // W2^T, rows padded to 68 floats
    __shared__ float4 ysh[4][68];            // per-wave y staging, 17-f4 group stride
    int tid = threadIdx.x;
    #pragma unroll
    for (int i = 0; i < 4; ++i) {
        int idx = i * 256 + tid;             // idx = f*16 + j
        w2t[(idx & 15) * 68 + (idx >> 4)] = W2[idx];
    }
    __syncthreads();

    int lane = tid & 63;
    int wv   = tid >> 6;                     // wave in block
    int grp  = lane >> 4;                    // 0..3
    int l16  = lane & 15;
    int g0   = lane & 48;                    // group base lane (absolute in wave)
    int node = ((blockIdx.x * 256 + tid) >> 6) * 4 + grp;   // exact: 25000 waves * 4
    int   b  = base[node];
    int   c  = cnt[node];
    float di = dinv[node];
    float4 acc = {0.f, 0.f, 0.f, 0.f};
    accb(acc, g1b[(size_t)node * 16 + l16]);           // self term

    for (int k0 = 0; k0 < c; k0 += 16) {
        int k = k0 + l16;
        int sidx = (k < c) ? csr_src[b + k] : 0;       // group-coalesced stage
        int nj = min(16, c - k0);
        int j = 0;
        for (; j + 4 <= nj; j += 4) {
            int s0 = __shfl(sidx, g0 + j + 0);
            int s1 = __shfl(sidx, g0 + j + 1);
            int s2 = __shfl(sidx, g0 + j + 2);
            int s3 = __shfl(sidx, g0 + j + 3);
            uint2 u0 = g1b[(size_t)s0 * 16 + l16];     // 4 independent 128B rows
            uint2 u1 = g1b[(size_t)s1 * 16 + l16];
            uint2 u2 = g1b[(size_t)s2 * 16 + l16];
            uint2 u3 = g1b[(size_t)s3 * 16 + l16];
            accb(acc, u0); accb(acc, u1); accb(acc, u2); accb(acc, u3);
        }
        for (; j < nj; ++j) {
            accb(acc, g1b[(size_t)__shfl(sidx, g0 + j) * 16 + l16]);
        }
    }

    // epilogue: y = di*relu(b1 + di*acc), transpose via LDS, y @ W2 -> g2b
    float4 bv = ((const float4*)b1)[l16];
    float4 y;
    y.x = fmaxf(fmaf(di, acc.x, bv.x), 0.f) * di;
    y.y = fmaxf(fmaf(di, acc.y, bv.y), 0.f) * di;
    y.z = fmaxf(fmaf(di, acc.z, bv.z), 0.f) * di;
    y.w = fmaxf(fmaf(di, acc.w, bv.w), 0.f) * di;
    ysh[wv][grp * 17 + l16] = y;             // wave-internal, DS-pipe ordered

    float o = 0.f;                           // this lane's output column j = l16
    #pragma unroll
    for (int f4 = 0; f4 < 16; ++f4) {
        float4 yv = ysh[wv][grp * 17 + f4];            // broadcast within group
        const float4* wr = (const float4*)&w2t[l16 * 68 + f4 * 4];
        float4 wv4 = *wr;
        o = fmaf(yv.x, wv4.x, o);
        o = fmaf(yv.y, wv4.y, o);
        o = fmaf(yv.z, wv4.z, o);
        o = fmaf(yv.w, wv4.w, o);
    }
    float o1 = __shfl_down(o, 1);
    float o2 = __shfl_down(o, 2);
    float o3 = __shfl_down(o, 3);
    if ((l16 & 3) == 0) {
        uint2 pk;
        pk.x = bfr(o)  | (bfr(o1) << 16);
        pk.y = bfr(o2) | (bfr(o3) << 16);
        g2b[(size_t)node * 4 + (l16 >> 2)] = pk;
    }
}

// ---------- gather layer 2: 4-lane group per node (16 nodes/wave), bf16 rows ----------
__global__ __launch_bounds__(256) void k_gather2(const int* __restrict__ csr_src,
                                                 const int* __restrict__ base,
                                                 const int* __restrict__ cnt,
                                                 const float* __restrict__ dinv,
                                                 const uint2* __restrict__ g2b,   // [N][4]
                                                 const float* __restrict__ b2,
                                                 float* __restrict__ out) {
    int tid  = threadIdx.x;
    int lane = tid & 63;
    int grp  = lane >> 2;                    // 0..15
    int l4   = lane & 3;
    int g0   = lane & 60;                    // group base lane
    int node = ((blockIdx.x * 256 + tid) >> 6) * 16 + grp;
    if (node >= N_NODES) return;
    int   b  = base[node];
    int   c  = cnt[node];
    float di = dinv[node];
    float4 acc = {0.f, 0.f, 0.f, 0.f};
    accb(acc, g2b[(size_t)node * 4 + l4]);             // self term

    for (int k0 = 0; k0 < c; k0 += 4) {
        int k = k0 + l4;
        int sidx = (k < c) ? csr_src[b + k] : 0;
        int nj = min(4, c - k0);
        if (nj == 4) {
            int s0 = __shfl(sidx, g0 + 0);
            int s1 = __shfl(sidx, g0 + 1);
            int s2 = __shfl(sidx, g0 + 2);
            int s3 = __shfl(sidx, g0 + 3);
            uint2 u0 = g2b[(size_t)s0 * 4 + l4];       // 4 independent 32B rows
            uint2 u1 = g2b[(size_t)s1 * 4 + l4];
            uint2 u2 = g2b[(size_t)s2 * 4 + l4];
            uint2 u3 = g2b[(size_t)s3 * 4 + l4];
            accb(acc, u0); accb(acc, u1); accb(acc, u2); accb(acc, u3);
        } else {
            for (int j = 0; j < nj; ++j)
                accb(acc, g2b[(size_t)__shfl(sidx, g0 + j) * 4 + l4]);
        }
    }
    float4 bv = ((const float4*)b2)[l4];
    float4 r  = { fmaf(di, acc.x, bv.x), fmaf(di, acc.y, bv.y),
                  fmaf(di, acc.z, bv.z), fmaf(di, acc.w, bv.w) };
    ((float4*)out)[(size_t)node * 4 + l4] = r;
}

extern "C" void kernel_launch(void* const* d_in, const int* in_sizes, int n_in,
                              void* d_out, int out_size, void* d_ws, size_t ws_size,
                              hipStream_t stream) {
    const float* x     = (const float*)d_in[0];
    const int*   edges = (const int*)d_in[1];              // int32 (harness converts)
    const float* W1    = (const float*)d_in[2];
    const float* b1    = (const float*)d_in[3];
    const float* W2    = (const float*)d_in[4];
    const float* b2    = (const float*)d_in[5];
    float*       out   = (float*)d_out;

    const int E = in_sizes[1] / 2;                         // 3,200,000

    // workspace (~32.8 MB), concurrently-live regions disjoint (R13 layout):
    //   [0, 14.0 MB):    pairs (build)  -> g1b (bf16 12.8 MB; live through gather1)
    //   [14.0, 17.2 MB): g2b (bf16, N*4 uint2 = 3.2 MB; written by gather1)
    //   [17.2, 31.2 MB): csr_src (NBKT*CAP ints)
    //   [31.2, ...):     nbase | ncnt | dinv | bkt_tail
    int*   pairs   = (int*)d_ws;                           // NBKT*CAP ints
    uint2* g1b     = (uint2*)d_ws;                         // N*16 uint2 (bf16 rows)
    uint2* g2b     = (uint2*)((float*)d_ws + (size_t)NBKT * CAP);
    int*   csr_src = (int*)g2b + (size_t)N_NODES * 8 + 64; // after g2b (N*4 uint2 = N*8 int)
    int*   nbase   = csr_src + (size_t)NBKT * CAP;         // N
    int*   ncnt    = nbase + N_NODES;                      // N
    float* dinv    = (float*)(ncnt + N_NODES);             // N
    int*   bkt_tail= (int*)(dinv + N_NODES);               // NBKT*16

    const int nchunk = (E + CHUNK - 1) / CHUNK;            // 782

    // CSR build (single-pass padded-bucket sort by dst — R13 measured config)
    k_zero_b <<<(NBKT * BKT_PAD + 255) / 256, 256, 0, stream>>>(bkt_tail);
    k_bfill  <<<nchunk, 256, 0, stream>>>((const int2*)edges, bkt_tail, pairs, E);
    k_bnode  <<<NBKT, 1024, 0, stream>>>(pairs, bkt_tail, csr_src, nbase, ncnt, dinv);

    // layer 1 GEMM (R=4, 512-thread blocks — the one change vs R13)
    k_gemm1   <<<(N_NODES + 127) / 128, 512, 0, stream>>>(x, W1, dinv, g1b);

    // fused: gather1 + bias + relu + GEMM2 -> g2b
    k_gather1 <<<6250, 256, 0, stream>>>(csr_src, nbase, ncnt, dinv, g1b, b1, W2, g2b);

    // gather layer 2 -> out
    k_gather2 <<<1563, 256, 0, stream>>>(csr_src, nbase, ncnt, dinv, g2b, b2, out);
}

// Round 17
// 187.724 us; speedup vs baseline: 1.1188x; 1.0381x over previous
//
#include <hip/hip_runtime.h>

#define N_NODES 100000
#define F_IN    128
#define H_DIM   64
#define C_DIM   16
#define NBKT    391            // ceil(100000 / 256) buckets of 256 nodes (dst>>8)
#define BKT_PAD 16             // one bucket counter per 64B line
#define CHUNK   4096           // edges per block in bucket phases
#define CAP     8960           // padded bucket capacity (lambda=8192, +8.5 sigma)

__device__ __forceinline__ void fma4(float4& acc, float s, const float4& w) {
    acc.x = fmaf(s, w.x, acc.x);
    acc.y = fmaf(s, w.y, acc.y);
    acc.z = fmaf(s, w.z, acc.z);
    acc.w = fmaf(s, w.w, acc.w);
}
// f32 -> bf16 round-to-nearest-even
__device__ __forceinline__ unsigned bfr(float f) {
    unsigned u = __float_as_uint(f);
    return (u + (((u >> 16) & 1u) + 0x7FFFu)) >> 16;
}
// unpack-add: two packed bf16 pairs -> 4 f32 adds
__device__ __forceinline__ void accb(float4& a, uint2 u) {
    a.x += __uint_as_float(u.x << 16);
    a.y += __uint_as_float(u.x & 0xFFFF0000u);
    a.z += __uint_as_float(u.y << 16);
    a.w += __uint_as_float(u.y & 0xFFFF0000u);
}

// ---------- CSR build ----------
__global__ void k_zero_b(int* __restrict__ b) {
    int i = blockIdx.x * blockDim.x + threadIdx.x;
    if (i < NBKT * BKT_PAD) b[i] = 0;
}

// v2: LDS hist (rank from atomic return) -> 391-scan -> block-local counting
// sort in LDS -> COALESCED bucket-grouped writeout (runs contiguous per wave).
// pairs packed: (src<<8) | (dst & 255)
__global__ __launch_bounds__(256) void k_bfill(const int2* __restrict__ edges,
                                               int* __restrict__ bkt_tail,
                                               int* __restrict__ pairs, int E) {
    __shared__ int2 sp[CHUNK];               // 32 KB block-sorted edge staging
    __shared__ int  cnt[NBKT];
    __shared__ int  lbase[NBKT];             // block-local exclusive base
    __shared__ int  row[NBKT];               // global base (bkt_tail reservation)
    __shared__ int  scn[512];
    int t = threadIdx.x;
    for (int i = t; i < NBKT; i += 256) cnt[i] = 0;
    __syncthreads();
    int base = blockIdx.x * CHUNK;
    int m    = min(E - base, CHUNK);         // edges in this block
    int2 ed[16];                             // static idx via unroll (rule #20)
    int  rk[16];
    #pragma unroll
    for (int i = 0; i < 16; ++i) {
        int e = i * 256 + t;
        if (e < m) {
            ed[i] = edges[base + e];
            rk[i] = atomicAdd(&cnt[ed[i].y >> 8], 1);   // rank within (block,bucket)
        }
    }
    __syncthreads();
    // 512-wide inclusive scan of cnt (padded), 256 threads x 2 slots
    scn[t]       = (t < NBKT) ? cnt[t] : 0;
    scn[t + 256] = (t + 256 < NBKT) ? cnt[t + 256] : 0;
    __syncthreads();
    #pragma unroll
    for (int off = 1; off < 512; off <<= 1) {
        int v0 = (t >= off) ? scn[t - off] : 0;
        int v1 = (t + 256 >= off) ? scn[t + 256 - off] : 0;
        __syncthreads();
        scn[t] += v0;
        scn[t + 256] += v1;
        __syncthreads();
    }
    for (int b = t; b < NBKT; b += 256) {
        int c = cnt[b];
        lbase[b] = scn[b] - c;                               // exclusive
        row[b]   = c ? atomicAdd(&bkt_tail[b * BKT_PAD], c) : 0;
    }
    __syncthreads();
    // block-local counting sort: scatter edges into LDS by (bucket, rank)
    #pragma unroll
    for (int i = 0; i < 16; ++i) {
        int e = i * 256 + t;
        if (e < m) sp[lbase[ed[i].y >> 8] + rk[i]] = ed[i];
    }
    __syncthreads();
    // coalesced writeout: consecutive lanes -> consecutive sorted slots ->
    // contiguous addresses within each bucket run (~10.5 ints)
    #pragma unroll
    for (int i = 0; i < 16; ++i) {
        int idx = i * 256 + t;
        if (idx < m) {
            int2 p   = sp[idx];
            int  bkt = p.y >> 8;
            int  wpos = row[bkt] + (idx - lbase[bkt]);
            if (wpos < CAP) pairs[bkt * CAP + wpos] = (p.x << 8) | (p.y & 255);
        }
    }
}

// one block per bucket, 1024 threads (grid 391 = 1.5 blocks/CU; big blocks give
// the CU 16 waves for latency hiding). Measured ~11 us in R13 accounting.
__global__ __launch_bounds__(1024) void k_bnode(const int* __restrict__ pairs,
                                                const int* __restrict__ bkt_tail,
                                                int* __restrict__ csr_src,
                                                int* __restrict__ node_base,
                                                int* __restrict__ node_cnt,
                                                float* __restrict__ dinv) {
    __shared__ int sc[CAP];                 // 35 KB staged csr (src ids by local pos)
    __shared__ int cnt[256];
    __shared__ int row[256];
    __shared__ int wsum[4];
    int b = blockIdx.x;
    int t = threadIdx.x;
    if (t < 256) cnt[t] = 0;
    __syncthreads();
    int start = b * CAP;
    int m     = min(bkt_tail[b * BKT_PAD], CAP);
    for (int e = t; e < m; e += 1024)
        atomicAdd(&cnt[pairs[start + e] & 255], 1);     // pass 1 (L2-hot)
    __syncthreads();
    if (t < 256) {
        int c = cnt[t];
        // 256-wide exclusive scan: wave shfl scan + cross-wave combine
        int lane = t & 63, wv = t >> 6;
        int v = c;
        #pragma unroll
        for (int off = 1; off < 64; off <<= 1) {
            int u = __shfl_up(v, off);
            if (lane >= off) v += u;
        }
        if (lane == 63) wsum[wv] = v;
        __syncthreads();
        int woff = 0;
        #pragma unroll
        for (int w = 0; w < 4; ++w) woff += (w < wv) ? wsum[w] : 0;
        int incl = v + woff;                // inclusive over 256
        row[t] = incl - c;                  // local exclusive base
        int node = b * 256 + t;
        if (node < N_NODES) {
            node_base[node] = start + incl - c;
            node_cnt[node]  = c;
            dinv[node]      = rsqrtf((float)(c + 1));   // deg = cnt + 1 (self loop)
        }
    } else {
        __syncthreads();                    // match the scan's inner barrier
    }
    __syncthreads();
    for (int e = t; e < m; e += 1024) {
        int p   = pairs[start + e];                 // pass 2 (L2-hot)
        int pos = atomicAdd(&row[p & 255], 1);      // LDS atomic, local pos
        sc[pos] = ((unsigned)p) >> 8;
    }
    __syncthreads();
    for (int e = t; e < m; e += 1024)
        csr_src[start + e] = sc[e];                 // coalesced copy-out
}

// ---------- GEMM1 (R=4, 512 threads): 128 rows/block, 4 rows x 4 cols/thread ----
__global__ __launch_bounds__(512) void k_gemm1(const float* __restrict__ x,
                                               const float* __restrict__ W1,
                                               const float* __restrict__ dinv,
                                               uint2* __restrict__ g1b) {
    __shared__ float4 wlds[F_IN * 16];               // [k][colq] 32 KB
    int tid = threadIdx.x;
    const float4* w4 = (const float4*)W1;
    #pragma unroll
    for (int i = 0; i < 4; ++i) wlds[tid + 512 * i] = w4[tid + 512 * i];
    __syncthreads();

    int colq = tid & 15;
    int rq   = tid >> 4;                             // 0..31
    int row0 = blockIdx.x * 128 + rq * 4;
    const float4* xb = (const float4*)x;             // row stride = 32 float4

    float4 a0 = {0.f,0.f,0.f,0.f}, a1 = a0, a2 = a0, a3 = a0;
    size_t x0 = (size_t)(row0 + 0 < N_NODES ? row0 + 0 : 0) * 32;
    size_t x1 = (size_t)(row0 + 1 < N_NODES ? row0 + 1 : 0) * 32;
    size_t x2 = (size_t)(row0 + 2 < N_NODES ? row0 + 2 : 0) * 32;
    size_t x3 = (size_t)(row0 + 3 < N_NODES ? row0 + 3 : 0) * 32;

    #pragma unroll 4
    for (int k4 = 0; k4 < F_IN / 4; ++k4) {
        float4 w0 = wlds[(4 * k4 + 0) * 16 + colq];  // 4 LDS reads serve 64 fmas
        float4 w1 = wlds[(4 * k4 + 1) * 16 + colq];
        float4 w2 = wlds[(4 * k4 + 2) * 16 + colq];
        float4 w3 = wlds[(4 * k4 + 3) * 16 + colq];
        float4 v0 = xb[x0 + k4];                     // 4 independent broadcast loads
        float4 v1 = xb[x1 + k4];
        float4 v2 = xb[x2 + k4];
        float4 v3 = xb[x3 + k4];
        fma4(a0, v0.x, w0); fma4(a0, v0.y, w1); fma4(a0, v0.z, w2); fma4(a0, v0.w, w3);
        fma4(a1, v1.x, w0); fma4(a1, v1.y, w1); fma4(a1, v1.z, w2); fma4(a1, v1.w, w3);
        fma4(a2, v2.x, w0); fma4(a2, v2.y, w1); fma4(a2, v2.z, w2); fma4(a2, v2.w, w3);
        fma4(a3, v3.x, w0); fma4(a3, v3.y, w1); fma4(a3, v3.z, w2); fma4(a3, v3.w, w3);
    }
    #pragma unroll
    for (int j = 0; j < 4; ++j) {
        int r = row0 + j;
        if (r < N_NODES) {
            float4 aj = (j == 0) ? a0 : (j == 1) ? a1 : (j == 2) ? a2 : a3;
            float di = dinv[r];
            uint2 p;
            p.x = bfr(aj.x * di) | (bfr(aj.y * di) << 16);
            p.y = bfr(aj.z * di) | (bfr(aj.w * di) << 16);
            g1b[(size_t)r * 16 + colq] = p;
        }
    }
}

// ---------- fused gather1 + bias + relu + GEMM2 ----------
__global__ __launch_bounds__(256) void k_gather1(const int* __restrict__ csr_src,
                                                 const int* __restrict__ base,
                                                 const int* __restrict__ cnt,
                                                 const float* __restrict__ dinv,
                                                 const uint2* __restrict__ g1b,  // [N][16]
                                                 const float* __restrict__ b1,
                                                 const float* __restrict__ W2,   // [64][16]
                                                 uint2* __restrict__ g2b) {      // [N][4]
    __shared__ float  w2t[16 * 68];          // W2^T, rows padded to 68 floats
    __shared__ float4 ysh[4][68];            // per-wave y staging, 17-f4 group stride
    int tid = threadIdx.x;
    #pragma unroll
    for (int i = 0; i < 4; ++i) {
        int idx = i * 256 + tid;             // idx = f*16 + j
        w2t[(idx & 15) * 68 + (idx >> 4)] = W2[idx];
    }
    __syncthreads();

    int lane = tid & 63;
    int wv   = tid >> 6;                     // wave in block
    int grp  = lane >> 4;                    // 0..3
    int l16  = lane & 15;
    int g0   = lane & 48;                    // group base lane (absolute in wave)
    int node = ((blockIdx.x * 256 + tid) >> 6) * 4 + grp;   // exact: 25000 waves * 4
    int   b  = base[node];
    int   c  = cnt[node];
    float di = dinv[node];
    float4 acc = {0.f, 0.f, 0.f, 0.f};
    accb(acc, g1b[(size_t)node * 16 + l16]);           // self term

    for (int k0 = 0; k0 < c; k0 += 16) {
        int k = k0 + l16;
        int sidx = (k < c) ? csr_src[b + k] : 0;       // group-coalesced stage
        int nj = min(16, c - k0);
        int j = 0;
        for (; j + 4 <= nj; j += 4) {
            int s0 = __shfl(sidx, g0 + j + 0);
            int s1 = __shfl(sidx, g0 + j + 1);
            int s2 = __shfl(sidx, g0 + j + 2);
            int s3 = __shfl(sidx, g0 + j + 3);
            uint2 u0 = g1b[(size_t)s0 * 16 + l16];     // 4 independent 128B rows
            uint2 u1 = g1b[(size_t)s1 * 16 + l16];
            uint2 u2 = g1b[(size_t)s2 * 16 + l16];
            uint2 u3 = g1b[(size_t)s3 * 16 + l16];
            accb(acc, u0); accb(acc, u1); accb(acc, u2); accb(acc, u3);
        }
        for (; j < nj; ++j) {
            accb(acc, g1b[(size_t)__shfl(sidx, g0 + j) * 16 + l16]);
        }
    }

    // epilogue: y = di*relu(b1 + di*acc), transpose via LDS, y @ W2 -> g2b
    float4 bv = ((const float4*)b1)[l16];
    float4 y;
    y.x = fmaxf(fmaf(di, acc.x, bv.x), 0.f) * di;
    y.y = fmaxf(fmaf(di, acc.y, bv.y), 0.f) * di;
    y.z = fmaxf(fmaf(di, acc.z, bv.z), 0.f) * di;
    y.w = fmaxf(fmaf(di, acc.w, bv.w), 0.f) * di;
    ysh[wv][grp * 17 + l16] = y;             // wave-internal, DS-pipe ordered

    float o = 0.f;                           // this lane's output column j = l16
    #pragma unroll
    for (int f4 = 0; f4 < 16; ++f4) {
        float4 yv = ysh[wv][grp * 17 + f4];            // broadcast within group
        const float4* wr = (const float4*)&w2t[l16 * 68 + f4 * 4];
        float4 wv4 = *wr;
        o = fmaf(yv.x, wv4.x, o);
        o = fmaf(yv.y, wv4.y, o);
        o = fmaf(yv.z, wv4.z, o);
        o = fmaf(yv.w, wv4.w, o);
    }
    float o1 = __shfl_down(o, 1);
    float o2 = __shfl_down(o, 2);
    float o3 = __shfl_down(o, 3);
    if ((l16 & 3) == 0) {
        uint2 pk;
        pk.x = bfr(o)  | (bfr(o1) << 16);
        pk.y = bfr(o2) | (bfr(o3) << 16);
        g2b[(size_t)node * 4 + (l16 >> 2)] = pk;
    }
}

// ---------- gather layer 2: 4-lane group per node (16 nodes/wave), bf16 rows ----------
__global__ __launch_bounds__(256) void k_gather2(const int* __restrict__ csr_src,
                                                 const int* __restrict__ base,
                                                 const int* __restrict__ cnt,
                                                 const float* __restrict__ dinv,
                                                 const uint2* __restrict__ g2b,   // [N][4]
                                                 const float* __restrict__ b2,
                                                 float* __restrict__ out) {
    int tid  = threadIdx.x;
    int lane = tid & 63;
    int grp  = lane >> 2;                    // 0..15
    int l4   = lane & 3;
    int g0   = lane & 60;                    // group base lane
    int node = ((blockIdx.x * 256 + tid) >> 6) * 16 + grp;
    if (node >= N_NODES) return;
    int   b  = base[node];
    int   c  = cnt[node];
    float di = dinv[node];
    float4 acc = {0.f, 0.f, 0.f, 0.f};
    accb(acc, g2b[(size_t)node * 4 + l4]);             // self term

    for (int k0 = 0; k0 < c; k0 += 4) {
        int k = k0 + l4;
        int sidx = (k < c) ? csr_src[b + k] : 0;
        int nj = min(4, c - k0);
        if (nj == 4) {
            int s0 = __shfl(sidx, g0 + 0);
            int s1 = __shfl(sidx, g0 + 1);
            int s2 = __shfl(sidx, g0 + 2);
            int s3 = __shfl(sidx, g0 + 3);
            uint2 u0 = g2b[(size_t)s0 * 4 + l4];       // 4 independent 32B rows
            uint2 u1 = g2b[(size_t)s1 * 4 + l4];
            uint2 u2 = g2b[(size_t)s2 * 4 + l4];
            uint2 u3 = g2b[(size_t)s3 * 4 + l4];
            accb(acc, u0); accb(acc, u1); accb(acc, u2); accb(acc, u3);
        } else {
            for (int j = 0; j < nj; ++j)
                accb(acc, g2b[(size_t)__shfl(sidx, g0 + j) * 4 + l4]);
        }
    }
    float4 bv = ((const float4*)b2)[l4];
    float4 r  = { fmaf(di, acc.x, bv.x), fmaf(di, acc.y, bv.y),
                  fmaf(di, acc.z, bv.z), fmaf(di, acc.w, bv.w) };
    ((float4*)out)[(size_t)node * 4 + l4] = r;
}

extern "C" void kernel_launch(void* const* d_in, const int* in_sizes, int n_in,
                              void* d_out, int out_size, void* d_ws, size_t ws_size,
                              hipStream_t stream) {
    const float* x     = (const float*)d_in[0];
    const int*   edges = (const int*)d_in[1];              // int32 (harness converts)
    const float* W1    = (const float*)d_in[2];
    const float* b1    = (const float*)d_in[3];
    const float* W2    = (const float*)d_in[4];
    const float* b2    = (const float*)d_in[5];
    float*       out   = (float*)d_out;

    const int E = in_sizes[1] / 2;                         // 3,200,000

    // workspace (~32.8 MB), concurrently-live regions disjoint (R13 layout):
    //   [0, 14.0 MB):    pairs (build)  -> g1b (bf16 12.8 MB; live through gather1)
    //   [14.0, 17.2 MB): g2b (bf16, N*4 uint2 = 3.2 MB; written by gather1)
    //   [17.2, 31.2 MB): csr_src (NBKT*CAP ints)
    //   [31.2, ...):     nbase | ncnt | dinv | bkt_tail
    int*   pairs   = (int*)d_ws;                           // NBKT*CAP ints
    uint2* g1b     = (uint2*)d_ws;                         // N*16 uint2 (bf16 rows)
    uint2* g2b     = (uint2*)((float*)d_ws + (size_t)NBKT * CAP);
    int*   csr_src = (int*)g2b + (size_t)N_NODES * 8 + 64; // after g2b (N*4 uint2 = N*8 int)
    int*   nbase   = csr_src + (size_t)NBKT * CAP;         // N
    int*   ncnt    = nbase + N_NODES;                      // N
    float* dinv    = (float*)(ncnt + N_NODES);             // N
    int*   bkt_tail= (int*)(dinv + N_NODES);               // NBKT*16

    const int nchunk = (E + CHUNK - 1) / CHUNK;            // 782

    // CSR build (bfill v2: coalesced writeout — the one change vs R16)
    k_zero_b <<<(NBKT * BKT_PAD + 255) / 256, 256, 0, stream>>>(bkt_tail);
    k_bfill  <<<nchunk, 256, 0, stream>>>((const int2*)edges, bkt_tail, pairs, E);
    k_bnode  <<<NBKT, 1024, 0, stream>>>(pairs, bkt_tail, csr_src, nbase, ncnt, dinv);

    // layer 1 GEMM (R=4, 512-thread blocks)
    k_gemm1   <<<(N_NODES + 127) / 128, 512, 0, stream>>>(x, W1, dinv, g1b);

    // fused: gather1 + bias + relu + GEMM2 -> g2b
    k_gather1 <<<6250, 256, 0, stream>>>(csr_src, nbase, ncnt, dinv, g1b, b1, W2, g2b);

    // gather layer 2 -> out
    k_gather2 <<<1563, 256, 0, stream>>>(csr_src, nbase, ncnt, dinv, g2b, b2, out);
}

// Round 18
// 163.853 us; speedup vs baseline: 1.2818x; 1.1457x over previous
//
#include <hip/hip_runtime.h>

#define N_NODES 100000
#define F_IN    128
#define H_DIM   64
#define C_DIM   16
#define NBKT    391            // ceil(100000 / 256) buckets of 256 nodes (dst>>8)
#define BKT_PAD 16             // one bucket counter per 64B line
#define CHUNK   4096           // edges per block in bucket phases
#define CAP     8960           // padded bucket capacity (lambda=8192, +8.5 sigma)

typedef __attribute__((ext_vector_type(8))) short bf16x8;   // 8 bf16 (4 VGPRs)
typedef __attribute__((ext_vector_type(4))) float f32x4;    // MFMA accum

__device__ __forceinline__ void fma4(float4& acc, float s, const float4& w) {
    acc.x = fmaf(s, w.x, acc.x);
    acc.y = fmaf(s, w.y, acc.y);
    acc.z = fmaf(s, w.z, acc.z);
    acc.w = fmaf(s, w.w, acc.w);
}
// f32 -> bf16 round-to-nearest-even
__device__ __forceinline__ unsigned bfr(float f) {
    unsigned u = __float_as_uint(f);
    return (u + (((u >> 16) & 1u) + 0x7FFFu)) >> 16;
}
// unpack-add: two packed bf16 pairs -> 4 f32 adds
__device__ __forceinline__ void accb(float4& a, uint2 u) {
    a.x += __uint_as_float(u.x << 16);
    a.y += __uint_as_float(u.x & 0xFFFF0000u);
    a.z += __uint_as_float(u.y << 16);
    a.w += __uint_as_float(u.y & 0xFFFF0000u);
}

// ---------- CSR build ----------
__global__ void k_zero_b(int* __restrict__ b) {
    int i = blockIdx.x * blockDim.x + threadIdx.x;
    if (i < NBKT * BKT_PAD) b[i] = 0;
}

// v2: LDS hist (rank from atomic return) -> 391-scan -> block-local counting
// sort in LDS -> coalesced bucket-grouped writeout.
__global__ __launch_bounds__(256) void k_bfill(const int2* __restrict__ edges,
                                               int* __restrict__ bkt_tail,
                                               int* __restrict__ pairs, int E) {
    __shared__ int2 sp[CHUNK];               // 32 KB block-sorted edge staging
    __shared__ int  cnt[NBKT];
    __shared__ int  lbase[NBKT];             // block-local exclusive base
    __shared__ int  row[NBKT];               // global base (bkt_tail reservation)
    __shared__ int  scn[512];
    int t = threadIdx.x;
    for (int i = t; i < NBKT; i += 256) cnt[i] = 0;
    __syncthreads();
    int base = blockIdx.x * CHUNK;
    int m    = min(E - base, CHUNK);         // edges in this block
    int2 ed[16];                             // static idx via unroll (rule #20)
    int  rk[16];
    #pragma unroll
    for (int i = 0; i < 16; ++i) {
        int e = i * 256 + t;
        if (e < m) {
            ed[i] = edges[base + e];
            rk[i] = atomicAdd(&cnt[ed[i].y >> 8], 1);   // rank within (block,bucket)
        }
    }
    __syncthreads();
    scn[t]       = (t < NBKT) ? cnt[t] : 0;
    scn[t + 256] = (t + 256 < NBKT) ? cnt[t + 256] : 0;
    __syncthreads();
    #pragma unroll
    for (int off = 1; off < 512; off <<= 1) {
        int v0 = (t >= off) ? scn[t - off] : 0;
        int v1 = (t + 256 >= off) ? scn[t + 256 - off] : 0;
        __syncthreads();
        scn[t] += v0;
        scn[t + 256] += v1;
        __syncthreads();
    }
    for (int b = t; b < NBKT; b += 256) {
        int c = cnt[b];
        lbase[b] = scn[b] - c;                               // exclusive
        row[b]   = c ? atomicAdd(&bkt_tail[b * BKT_PAD], c) : 0;
    }
    __syncthreads();
    #pragma unroll
    for (int i = 0; i < 16; ++i) {
        int e = i * 256 + t;
        if (e < m) sp[lbase[ed[i].y >> 8] + rk[i]] = ed[i];
    }
    __syncthreads();
    #pragma unroll
    for (int i = 0; i < 16; ++i) {
        int idx = i * 256 + t;
        if (idx < m) {
            int2 p   = sp[idx];
            int  bkt = p.y >> 8;
            int  wpos = row[bkt] + (idx - lbase[bkt]);
            if (wpos < CAP) pairs[bkt * CAP + wpos] = (p.x << 8) | (p.y & 255);
        }
    }
}

// one block per bucket, 1024 threads.
__global__ __launch_bounds__(1024) void k_bnode(const int* __restrict__ pairs,
                                                const int* __restrict__ bkt_tail,
                                                int* __restrict__ csr_src,
                                                int* __restrict__ node_base,
                                                int* __restrict__ node_cnt,
                                                float* __restrict__ dinv) {
    __shared__ int sc[CAP];                 // 35 KB staged csr (src ids by local pos)
    __shared__ int cnt[256];
    __shared__ int row[256];
    __shared__ int wsum[4];
    int b = blockIdx.x;
    int t = threadIdx.x;
    if (t < 256) cnt[t] = 0;
    __syncthreads();
    int start = b * CAP;
    int m     = min(bkt_tail[b * BKT_PAD], CAP);
    for (int e = t; e < m; e += 1024)
        atomicAdd(&cnt[pairs[start + e] & 255], 1);     // pass 1 (L2-hot)
    __syncthreads();
    if (t < 256) {
        int c = cnt[t];
        int lane = t & 63, wv = t >> 6;
        int v = c;
        #pragma unroll
        for (int off = 1; off < 64; off <<= 1) {
            int u = __shfl_up(v, off);
            if (lane >= off) v += u;
        }
        if (lane == 63) wsum[wv] = v;
        __syncthreads();
        int woff = 0;
        #pragma unroll
        for (int w = 0; w < 4; ++w) woff += (w < wv) ? wsum[w] : 0;
        int incl = v + woff;                // inclusive over 256
        row[t] = incl - c;                  // local exclusive base
        int node = b * 256 + t;
        if (node < N_NODES) {
            node_base[node] = start + incl - c;
            node_cnt[node]  = c;
            dinv[node]      = rsqrtf((float)(c + 1));   // deg = cnt + 1 (self loop)
        }
    } else {
        __syncthreads();                    // match the scan's inner barrier
    }
    __syncthreads();
    for (int e = t; e < m; e += 1024) {
        int p   = pairs[start + e];                 // pass 2 (L2-hot)
        int pos = atomicAdd(&row[p & 255], 1);      // LDS atomic, local pos
        sc[pos] = ((unsigned)p) >> 8;
    }
    __syncthreads();
    for (int e = t; e < m; e += 1024)
        csr_src[start + e] = sc[e];                 // coalesced copy-out
}

// ---------- GEMM1 v4 (MFMA bf16): wave = 16 rows x 64 cols, K=128 ----------
// g1b[N,64](bf16) = dinv[row] * (x[N,128] @ W1[128,64])
// A frag: lane gives x[row0 + (lane&15)][(lane>>4)*8 + i], 8 contiguous k (f32->bf16)
// B frag: lane gives W1^T[col = ct*16 + (lane&15)][same k range] from LDS
// C/D:    col = lane&15 (+ct*16), row = row0 + (lane>>4)*4 + reg    [m89]
__global__ __launch_bounds__(256) void k_gemm1(const float* __restrict__ x,
                                               const float* __restrict__ W1,
                                               const float* __restrict__ dinv,
                                               uint2* __restrict__ g1b) {
    __shared__ short wt[64][132];            // W1^T bf16, +4 pad (2-way conflicts only)
    int tid = threadIdx.x;
    {
        int n  = tid & 63;
        int k0 = (tid >> 6) * 32;
        #pragma unroll 8
        for (int k = 0; k < 32; ++k)
            wt[n][k0 + k] = (short)bfr(W1[(size_t)(k0 + k) * H_DIM + n]);
    }
    __syncthreads();

    int wave = tid >> 6, lane = tid & 63;
    int tile = blockIdx.x * 4 + wave;        // 16-row tile id
    bool valid = tile < N_NODES / 16;        // 6250 tiles exactly
    int row0 = (valid ? tile : 0) * 16;
    int l15  = lane & 15;
    int kg   = lane >> 4;                    // 0..3 (k-group of 8)
    const float* xrow = x + (size_t)(row0 + l15) * F_IN;

    f32x4 ac0 = {0.f,0.f,0.f,0.f}, ac1 = ac0, ac2 = ac0, ac3 = ac0;
    #pragma unroll
    for (int ks = 0; ks < 4; ++ks) {         // K = 128 = 4 x 32
        int kb = ks * 32 + kg * 8;
        float4 p0 = *(const float4*)(xrow + kb);
        float4 p1 = *(const float4*)(xrow + kb + 4);
        bf16x8 a;
        a[0] = (short)bfr(p0.x); a[1] = (short)bfr(p0.y);
        a[2] = (short)bfr(p0.z); a[3] = (short)bfr(p0.w);
        a[4] = (short)bfr(p1.x); a[5] = (short)bfr(p1.y);
        a[6] = (short)bfr(p1.z); a[7] = (short)bfr(p1.w);
        bf16x8 b0 = *(const bf16x8*)&wt[l15     ][kb];
        bf16x8 b1 = *(const bf16x8*)&wt[l15 + 16][kb];
        bf16x8 b2 = *(const bf16x8*)&wt[l15 + 32][kb];
        bf16x8 b3 = *(const bf16x8*)&wt[l15 + 48][kb];
        ac0 = __builtin_amdgcn_mfma_f32_16x16x32_bf16(a, b0, ac0, 0, 0, 0);
        ac1 = __builtin_amdgcn_mfma_f32_16x16x32_bf16(a, b1, ac1, 0, 0, 0);
        ac2 = __builtin_amdgcn_mfma_f32_16x16x32_bf16(a, b2, ac2, 0, 0, 0);
        ac3 = __builtin_amdgcn_mfma_f32_16x16x32_bf16(a, b3, ac3, 0, 0, 0);
    }
    if (!valid) return;

    int rbase = row0 + kg * 4;               // this lane's 4 output rows
    #pragma unroll
    for (int r = 0; r < 4; ++r) {
        float di = dinv[rbase + r];
        size_t gro = (size_t)(rbase + r) * 16;
        #pragma unroll
        for (int ct = 0; ct < 4; ++ct) {
            float v = ((ct == 0) ? ac0[r] : (ct == 1) ? ac1[r] :
                       (ct == 2) ? ac2[r] : ac3[r]) * di;
            float v1 = __shfl_down(v, 1);
            float v2 = __shfl_down(v, 2);
            float v3 = __shfl_down(v, 3);
            if ((l15 & 3) == 0) {            // lanes l15 = 0,4,8,12 write 4 cols
                uint2 pk;
                pk.x = bfr(v)  | (bfr(v1) << 16);
                pk.y = bfr(v2) | (bfr(v3) << 16);
                g1b[gro + ct * 4 + (l15 >> 2)] = pk;
            }
        }
    }
}

// ---------- fused gather1 + bias + relu + GEMM2 ----------
__global__ __launch_bounds__(256) void k_gather1(const int* __restrict__ csr_src,
                                                 const int* __restrict__ base,
                                                 const int* __restrict__ cnt,
                                                 const float* __restrict__ dinv,
                                                 const uint2* __restrict__ g1b,  // [N][16]
                                                 const float* __restrict__ b1,
                                                 const float* __restrict__ W2,   // [64][16]
                                                 uint2* __restrict__ g2b) {      // [N][4]
    __shared__ float  w2t[16 * 68];          // W2^T, rows padded to 68 floats
    __shared__ float4 ysh[4][68];            // per-wave y staging, 17-f4 group stride
    int tid = threadIdx.x;
    #pragma unroll
    for (int i = 0; i < 4; ++i) {
        int idx = i * 256 + tid;             // idx = f*16 + j
        w2t[(idx & 15) * 68 + (idx >> 4)] = W2[idx];
    }
    __syncthreads();

    int lane = tid & 63;
    int wv   = tid >> 6;                     // wave in block
    int grp  = lane >> 4;                    // 0..3
    int l16  = lane & 15;
    int g0   = lane & 48;                    // group base lane (absolute in wave)
    int node = ((blockIdx.x * 256 + tid) >> 6) * 4 + grp;   // exact: 25000 waves * 4
    int   b  = base[node];
    int   c  = cnt[node];
    float di = dinv[node];
    float4 acc = {0.f, 0.f, 0.f, 0.f};
    accb(acc, g1b[(size_t)node * 16 + l16]);           // self term

    for (int k0 = 0; k0 < c; k0 += 16) {
        int k = k0 + l16;
        int sidx = (k < c) ? csr_src[b + k] : 0;       // group-coalesced stage
        int nj = min(16, c - k0);
        int j = 0;
        for (; j + 4 <= nj; j += 4) {
            int s0 = __shfl(sidx, g0 + j + 0);
            int s1 = __shfl(sidx, g0 + j + 1);
            int s2 = __shfl(sidx, g0 + j + 2);
            int s3 = __shfl(sidx, g0 + j + 3);
            uint2 u0 = g1b[(size_t)s0 * 16 + l16];     // 4 independent 128B rows
            uint2 u1 = g1b[(size_t)s1 * 16 + l16];
            uint2 u2 = g1b[(size_t)s2 * 16 + l16];
            uint2 u3 = g1b[(size_t)s3 * 16 + l16];
            accb(acc, u0); accb(acc, u1); accb(acc, u2); accb(acc, u3);
        }
        for (; j < nj; ++j) {
            accb(acc, g1b[(size_t)__shfl(sidx, g0 + j) * 16 + l16]);
        }
    }

    // epilogue: y = di*relu(b1 + di*acc), transpose via LDS, y @ W2 -> g2b
    float4 bv = ((const float4*)b1)[l16];
    float4 y;
    y.x = fmaxf(fmaf(di, acc.x, bv.x), 0.f) * di;
    y.y = fmaxf(fmaf(di, acc.y, bv.y), 0.f) * di;
    y.z = fmaxf(fmaf(di, acc.z, bv.z), 0.f) * di;
    y.w = fmaxf(fmaf(di, acc.w, bv.w), 0.f) * di;
    ysh[wv][grp * 17 + l16] = y;             // wave-internal, DS-pipe ordered

    float o = 0.f;                           // this lane's output column j = l16
    #pragma unroll
    for (int f4 = 0; f4 < 16; ++f4) {
        float4 yv = ysh[wv][grp * 17 + f4];            // broadcast within group
        const float4* wr = (const float4*)&w2t[l16 * 68 + f4 * 4];
        float4 wv4 = *wr;
        o = fmaf(yv.x, wv4.x, o);
        o = fmaf(yv.y, wv4.y, o);
        o = fmaf(yv.z, wv4.z, o);
        o = fmaf(yv.w, wv4.w, o);
    }
    float o1 = __shfl_down(o, 1);
    float o2 = __shfl_down(o, 2);
    float o3 = __shfl_down(o, 3);
    if ((l16 & 3) == 0) {
        uint2 pk;
        pk.x = bfr(o)  | (bfr(o1) << 16);
        pk.y = bfr(o2) | (bfr(o3) << 16);
        g2b[(size_t)node * 4 + (l16 >> 2)] = pk;
    }
}

// ---------- gather layer 2: 4-lane group per node (16 nodes/wave), bf16 rows ----------
__global__ __launch_bounds__(256) void k_gather2(const int* __restrict__ csr_src,
                                                 const int* __restrict__ base,
                                                 const int* __restrict__ cnt,
                                                 const float* __restrict__ dinv,
                                                 const uint2* __restrict__ g2b,   // [N][4]
                                                 const float* __restrict__ b2,
                                                 float* __restrict__ out) {
    int tid  = threadIdx.x;
    int lane = tid & 63;
    int grp  = lane >> 2;                    // 0..15
    int l4   = lane & 3;
    int g0   = lane & 60;                    // group base lane
    int node = ((blockIdx.x * 256 + tid) >> 6) * 16 + grp;
    if (node >= N_NODES) return;
    int   b  = base[node];
    int   c  = cnt[node];
    float di = dinv[node];
    float4 acc = {0.f, 0.f, 0.f, 0.f};
    accb(acc, g2b[(size_t)node * 4 + l4]);             // self term

    for (int k0 = 0; k0 < c; k0 += 4) {
        int k = k0 + l4;
        int sidx = (k < c) ? csr_src[b + k] : 0;
        int nj = min(4, c - k0);
        if (nj == 4) {
            int s0 = __shfl(sidx, g0 + 0);
            int s1 = __shfl(sidx, g0 + 1);
            int s2 = __shfl(sidx, g0 + 2);
            int s3 = __shfl(sidx, g0 + 3);
            uint2 u0 = g2b[(size_t)s0 * 4 + l4];       // 4 independent 32B rows
            uint2 u1 = g2b[(size_t)s1 * 4 + l4];
            uint2 u2 = g2b[(size_t)s2 * 4 + l4];
            uint2 u3 = g2b[(size_t)s3 * 4 + l4];
            accb(acc, u0); accb(acc, u1); accb(acc, u2); accb(acc, u3);
        } else {
            for (int j = 0; j < nj; ++j)
                accb(acc, g2b[(size_t)__shfl(sidx, g0 + j) * 4 + l4]);
        }
    }
    float4 bv = ((const float4*)b2)[l4];
    float4 r  = { fmaf(di, acc.x, bv.x), fmaf(di, acc.y, bv.y),
                  fmaf(di, acc.z, bv.z), fmaf(di, acc.w, bv.w) };
    ((float4*)out)[(size_t)node * 4 + l4] = r;
}

extern "C" void kernel_launch(void* const* d_in, const int* in_sizes, int n_in,
                              void* d_out, int out_size, void* d_ws, size_t ws_size,
                              hipStream_t stream) {
    const float* x     = (const float*)d_in[0];
    const int*   edges = (const int*)d_in[1];              // int32 (harness converts)
    const float* W1    = (const float*)d_in[2];
    const float* b1    = (const float*)d_in[3];
    const float* W2    = (const float*)d_in[4];
    const float* b2    = (const float*)d_in[5];
    float*       out   = (float*)d_out;

    const int E = in_sizes[1] / 2;                         // 3,200,000

    // workspace (~32.8 MB), concurrently-live regions disjoint (R13 layout):
    //   [0, 14.0 MB):    pairs (build)  -> g1b (bf16 12.8 MB; live through gather1)
    //   [14.0, 17.2 MB): g2b (bf16, N*4 uint2 = 3.2 MB; written by gather1)
    //   [17.2, 31.2 MB): csr_src (NBKT*CAP ints)
    //   [31.2, ...):     nbase | ncnt | dinv | bkt_tail
    int*   pairs   = (int*)d_ws;                           // NBKT*CAP ints
    uint2* g1b     = (uint2*)d_ws;                         // N*16 uint2 (bf16 rows)
    uint2* g2b     = (uint2*)((float*)d_ws + (size_t)NBKT * CAP);
    int*   csr_src = (int*)g2b + (size_t)N_NODES * 8 + 64; // after g2b (N*4 uint2 = N*8 int)
    int*   nbase   = csr_src + (size_t)NBKT * CAP;         // N
    int*   ncnt    = nbase + N_NODES;                      // N
    float* dinv    = (float*)(ncnt + N_NODES);             // N
    int*   bkt_tail= (int*)(dinv + N_NODES);               // NBKT*16

    const int nchunk = (E + CHUNK - 1) / CHUNK;            // 782

    // CSR build
    k_zero_b <<<(NBKT * BKT_PAD + 255) / 256, 256, 0, stream>>>(bkt_tail);
    k_bfill  <<<nchunk, 256, 0, stream>>>((const int2*)edges, bkt_tail, pairs, E);
    k_bnode  <<<NBKT, 1024, 0, stream>>>(pairs, bkt_tail, csr_src, nbase, ncnt, dinv);

    // layer 1 GEMM (MFMA bf16 — the one change vs R17): 6250 tiles, 4 waves/block
    k_gemm1   <<<(N_NODES / 16 + 3) / 4, 256, 0, stream>>>(x, W1, dinv, g1b);

    // fused: gather1 + bias + relu + GEMM2 -> g2b
    k_gather1 <<<6250, 256, 0, stream>>>(csr_src, nbase, ncnt, dinv, g1b, b1, W2, g2b);

    // gather layer 2 -> out
    k_gather2 <<<1563, 256, 0, stream>>>(csr_src, nbase, ncnt, dinv, g2b, b2, out);
}

// Round 19
// 145.071 us; speedup vs baseline: 1.4477x; 1.1295x over previous
//
#include <hip/hip_runtime.h>

#define N_NODES 100000
#define F_IN    128
#define H_DIM   64
#define C_DIM   16
#define NBKT    391            // ceil(100000 / 256) buckets of 256 nodes (dst>>8)
#define BKT_PAD 16             // one bucket counter per 64B line
#define CHUNK   8192           // edges per block in bfill (v3: halves run count)
#define CAP     8960           // padded bucket capacity (lambda=8192, +8.5 sigma)

typedef __attribute__((ext_vector_type(8))) short bf16x8;   // 8 bf16 (4 VGPRs)
typedef __attribute__((ext_vector_type(4))) float f32x4;    // MFMA accum

__device__ __forceinline__ void fma4(float4& acc, float s, const float4& w) {
    acc.x = fmaf(s, w.x, acc.x);
    acc.y = fmaf(s, w.y, acc.y);
    acc.z = fmaf(s, w.z, acc.z);
    acc.w = fmaf(s, w.w, acc.w);
}
// f32 -> bf16 round-to-nearest-even
__device__ __forceinline__ unsigned bfr(float f) {
    unsigned u = __float_as_uint(f);
    return (u + (((u >> 16) & 1u) + 0x7FFFu)) >> 16;
}
// unpack-add: two packed bf16 pairs -> 4 f32 adds
__device__ __forceinline__ void accb(float4& a, uint2 u) {
    a.x += __uint_as_float(u.x << 16);
    a.y += __uint_as_float(u.x & 0xFFFF0000u);
    a.z += __uint_as_float(u.y << 16);
    a.w += __uint_as_float(u.y & 0xFFFF0000u);
}

// ---------- CSR build ----------
// bfill v3: CHUNK=8192, 512 threads. LDS hist (rank from atomic return) ->
// 391-scan -> block-local counting sort in LDS -> coalesced writeout.
// Runs per (block,bucket) ~21 ints -> ~22.5 MB dirty lines (vs 32 MB at 4096).
__global__ __launch_bounds__(512) void k_bfill(const int2* __restrict__ edges,
                                               int* __restrict__ bkt_tail,
                                               int* __restrict__ pairs, int E) {
    __shared__ int2 sp[CHUNK];               // 64 KB block-sorted edge staging
    __shared__ int  cnt[NBKT];
    __shared__ int  lbase[NBKT];             // block-local exclusive base
    __shared__ int  row[NBKT];               // global base (bkt_tail reservation)
    __shared__ int  scn[512];
    int t = threadIdx.x;
    for (int i = t; i < NBKT; i += 512) cnt[i] = 0;
    __syncthreads();
    int base = blockIdx.x * CHUNK;
    int m    = min(E - base, CHUNK);         // edges in this block
    int2 ed[16];                             // static idx via unroll (rule #20)
    int  rk[16];
    #pragma unroll
    for (int i = 0; i < 16; ++i) {
        int e = i * 512 + t;
        if (e < m) {
            ed[i] = edges[base + e];
            rk[i] = atomicAdd(&cnt[ed[i].y >> 8], 1);   // rank within (block,bucket)
        }
    }
    __syncthreads();
    scn[t] = (t < NBKT) ? cnt[t] : 0;
    __syncthreads();
    #pragma unroll
    for (int off = 1; off < 512; off <<= 1) {
        int v = (t >= off) ? scn[t - off] : 0;
        __syncthreads();
        scn[t] += v;
        __syncthreads();
    }
    for (int b = t; b < NBKT; b += 512) {
        int c = cnt[b];
        lbase[b] = scn[b] - c;                               // exclusive
        row[b]   = c ? atomicAdd(&bkt_tail[b * BKT_PAD], c) : 0;
    }
    __syncthreads();
    // block-local counting sort: scatter edges into LDS by (bucket, rank)
    #pragma unroll
    for (int i = 0; i < 16; ++i) {
        int e = i * 512 + t;
        if (e < m) sp[lbase[ed[i].y >> 8] + rk[i]] = ed[i];
    }
    __syncthreads();
    // coalesced writeout: consecutive lanes -> contiguous run positions
    #pragma unroll
    for (int i = 0; i < 16; ++i) {
        int idx = i * 512 + t;
        if (idx < m) {
            int2 p   = sp[idx];
            int  bkt = p.y >> 8;
            int  wpos = row[bkt] + (idx - lbase[bkt]);
            if (wpos < CAP) pairs[bkt * CAP + wpos] = (p.x << 8) | (p.y & 255);
        }
    }
}

// one block per bucket, 1024 threads.
__global__ __launch_bounds__(1024) void k_bnode(const int* __restrict__ pairs,
                                                const int* __restrict__ bkt_tail,
                                                int* __restrict__ csr_src,
                                                int* __restrict__ node_base,
                                                int* __restrict__ node_cnt,
                                                float* __restrict__ dinv) {
    __shared__ int sc[CAP];                 // 35 KB staged csr (src ids by local pos)
    __shared__ int cnt[256];
    __shared__ int row[256];
    __shared__ int wsum[4];
    int b = blockIdx.x;
    int t = threadIdx.x;
    if (t < 256) cnt[t] = 0;
    __syncthreads();
    int start = b * CAP;
    int m     = min(bkt_tail[b * BKT_PAD], CAP);
    for (int e = t; e < m; e += 1024)
        atomicAdd(&cnt[pairs[start + e] & 255], 1);     // pass 1 (L2-hot)
    __syncthreads();
    if (t < 256) {
        int c = cnt[t];
        int lane = t & 63, wv = t >> 6;
        int v = c;
        #pragma unroll
        for (int off = 1; off < 64; off <<= 1) {
            int u = __shfl_up(v, off);
            if (lane >= off) v += u;
        }
        if (lane == 63) wsum[wv] = v;
        __syncthreads();
        int woff = 0;
        #pragma unroll
        for (int w = 0; w < 4; ++w) woff += (w < wv) ? wsum[w] : 0;
        int incl = v + woff;                // inclusive over 256
        row[t] = incl - c;                  // local exclusive base
        int node = b * 256 + t;
        if (node < N_NODES) {
            node_base[node] = start + incl - c;
            node_cnt[node]  = c;
            dinv[node]      = rsqrtf((float)(c + 1));   // deg = cnt + 1 (self loop)
        }
    } else {
        __syncthreads();                    // match the scan's inner barrier
    }
    __syncthreads();
    for (int e = t; e < m; e += 1024) {
        int p   = pairs[start + e];                 // pass 2 (L2-hot)
        int pos = atomicAdd(&row[p & 255], 1);      // LDS atomic, local pos
        sc[pos] = ((unsigned)p) >> 8;
    }
    __syncthreads();
    for (int e = t; e < m; e += 1024)
        csr_src[start + e] = sc[e];                 // coalesced copy-out
}

// ---------- GEMM1 v4 (MFMA bf16): wave = 16 rows x 64 cols, K=128 ----------
__global__ __launch_bounds__(256) void k_gemm1(const float* __restrict__ x,
                                               const float* __restrict__ W1,
                                               const float* __restrict__ dinv,
                                               uint2* __restrict__ g1b) {
    __shared__ short wt[64][132];            // W1^T bf16, +4 pad (2-way conflicts only)
    int tid = threadIdx.x;
    {
        int n  = tid & 63;
        int k0 = (tid >> 6) * 32;
        #pragma unroll 8
        for (int k = 0; k < 32; ++k)
            wt[n][k0 + k] = (short)bfr(W1[(size_t)(k0 + k) * H_DIM + n]);
    }
    __syncthreads();

    int wave = tid >> 6, lane = tid & 63;
    int tile = blockIdx.x * 4 + wave;        // 16-row tile id
    bool valid = tile < N_NODES / 16;        // 6250 tiles exactly
    int row0 = (valid ? tile : 0) * 16;
    int l15  = lane & 15;
    int kg   = lane >> 4;                    // 0..3 (k-group of 8)
    const float* xrow = x + (size_t)(row0 + l15) * F_IN;

    f32x4 ac0 = {0.f,0.f,0.f,0.f}, ac1 = ac0, ac2 = ac0, ac3 = ac0;
    #pragma unroll
    for (int ks = 0; ks < 4; ++ks) {         // K = 128 = 4 x 32
        int kb = ks * 32 + kg * 8;
        float4 p0 = *(const float4*)(xrow + kb);
        float4 p1 = *(const float4*)(xrow + kb + 4);
        bf16x8 a;
        a[0] = (short)bfr(p0.x); a[1] = (short)bfr(p0.y);
        a[2] = (short)bfr(p0.z); a[3] = (short)bfr(p0.w);
        a[4] = (short)bfr(p1.x); a[5] = (short)bfr(p1.y);
        a[6] = (short)bfr(p1.z); a[7] = (short)bfr(p1.w);
        bf16x8 b0 = *(const bf16x8*)&wt[l15     ][kb];
        bf16x8 b1 = *(const bf16x8*)&wt[l15 + 16][kb];
        bf16x8 b2 = *(const bf16x8*)&wt[l15 + 32][kb];
        bf16x8 b3 = *(const bf16x8*)&wt[l15 + 48][kb];
        ac0 = __builtin_amdgcn_mfma_f32_16x16x32_bf16(a, b0, ac0, 0, 0, 0);
        ac1 = __builtin_amdgcn_mfma_f32_16x16x32_bf16(a, b1, ac1, 0, 0, 0);
        ac2 = __builtin_amdgcn_mfma_f32_16x16x32_bf16(a, b2, ac2, 0, 0, 0);
        ac3 = __builtin_amdgcn_mfma_f32_16x16x32_bf16(a, b3, ac3, 0, 0, 0);
    }
    if (!valid) return;

    int rbase = row0 + kg * 4;               // this lane's 4 output rows
    #pragma unroll
    for (int r = 0; r < 4; ++r) {
        float di = dinv[rbase + r];
        size_t gro = (size_t)(rbase + r) * 16;
        #pragma unroll
        for (int ct = 0; ct < 4; ++ct) {
            float v = ((ct == 0) ? ac0[r] : (ct == 1) ? ac1[r] :
                       (ct == 2) ? ac2[r] : ac3[r]) * di;
            float v1 = __shfl_down(v, 1);
            float v2 = __shfl_down(v, 2);
            float v3 = __shfl_down(v, 3);
            if ((l15 & 3) == 0) {            // lanes l15 = 0,4,8,12 write 4 cols
                uint2 pk;
                pk.x = bfr(v)  | (bfr(v1) << 16);
                pk.y = bfr(v2) | (bfr(v3) << 16);
                g1b[gro + ct * 4 + (l15 >> 2)] = pk;
            }
        }
    }
}

// ---------- fused gather1 + bias + relu + GEMM2 ----------
__global__ __launch_bounds__(256) void k_gather1(const int* __restrict__ csr_src,
                                                 const int* __restrict__ base,
                                                 const int* __restrict__ cnt,
                                                 const float* __restrict__ dinv,
                                                 const uint2* __restrict__ g1b,  // [N][16]
                                                 const float* __restrict__ b1,
                                                 const float* __restrict__ W2,   // [64][16]
                                                 uint2* __restrict__ g2b) {      // [N][4]
    __shared__ float  w2t[16 * 68];          // W2^T, rows padded to 68 floats
    __shared__ float4 ysh[4][68];            // per-wave y staging, 17-f4 group stride
    int tid = threadIdx.x;
    #pragma unroll
    for (int i = 0; i < 4; ++i) {
        int idx = i * 256 + tid;             // idx = f*16 + j
        w2t[(idx & 15) * 68 + (idx >> 4)] = W2[idx];
    }
    __syncthreads();

    int lane = tid & 63;
    int wv   = tid >> 6;                     // wave in block
    int grp  = lane >> 4;                    // 0..3
    int l16  = lane & 15;
    int g0   = lane & 48;                    // group base lane (absolute in wave)
    int node = ((blockIdx.x * 256 + tid) >> 6) * 4 + grp;   // exact: 25000 waves * 4
    int   b  = base[node];
    int   c  = cnt[node];
    float di = dinv[node];
    float4 acc = {0.f, 0.f, 0.f, 0.f};
    accb(acc, g1b[(size_t)node * 16 + l16]);           // self term

    for (int k0 = 0; k0 < c; k0 += 16) {
        int k = k0 + l16;
        int sidx = (k < c) ? csr_src[b + k] : 0;       // group-coalesced stage
        int nj = min(16, c - k0);
        int j = 0;
        for (; j + 4 <= nj; j += 4) {
            int s0 = __shfl(sidx, g0 + j + 0);
            int s1 = __shfl(sidx, g0 + j + 1);
            int s2 = __shfl(sidx, g0 + j + 2);
            int s3 = __shfl(sidx, g0 + j + 3);
            uint2 u0 = g1b[(size_t)s0 * 16 + l16];     // 4 independent 128B rows
            uint2 u1 = g1b[(size_t)s1 * 16 + l16];
            uint2 u2 = g1b[(size_t)s2 * 16 + l16];
            uint2 u3 = g1b[(size_t)s3 * 16 + l16];
            accb(acc, u0); accb(acc, u1); accb(acc, u2); accb(acc, u3);
        }
        for (; j < nj; ++j) {
            accb(acc, g1b[(size_t)__shfl(sidx, g0 + j) * 16 + l16]);
        }
    }

    // epilogue: y = di*relu(b1 + di*acc), transpose via LDS, y @ W2 -> g2b
    float4 bv = ((const float4*)b1)[l16];
    float4 y;
    y.x = fmaxf(fmaf(di, acc.x, bv.x), 0.f) * di;
    y.y = fmaxf(fmaf(di, acc.y, bv.y), 0.f) * di;
    y.z = fmaxf(fmaf(di, acc.z, bv.z), 0.f) * di;
    y.w = fmaxf(fmaf(di, acc.w, bv.w), 0.f) * di;
    ysh[wv][grp * 17 + l16] = y;             // wave-internal, DS-pipe ordered

    float o = 0.f;                           // this lane's output column j = l16
    #pragma unroll
    for (int f4 = 0; f4 < 16; ++f4) {
        float4 yv = ysh[wv][grp * 17 + f4];            // broadcast within group
        const float4* wr = (const float4*)&w2t[l16 * 68 + f4 * 4];
        float4 wv4 = *wr;
        o = fmaf(yv.x, wv4.x, o);
        o = fmaf(yv.y, wv4.y, o);
        o = fmaf(yv.z, wv4.z, o);
        o = fmaf(yv.w, wv4.w, o);
    }
    float o1 = __shfl_down(o, 1);
    float o2 = __shfl_down(o, 2);
    float o3 = __shfl_down(o, 3);
    if ((l16 & 3) == 0) {
        uint2 pk;
        pk.x = bfr(o)  | (bfr(o1) << 16);
        pk.y = bfr(o2) | (bfr(o3) << 16);
        g2b[(size_t)node * 4 + (l16 >> 2)] = pk;
    }
}

// ---------- gather layer 2: 4-lane group per node (16 nodes/wave), bf16 rows ----------
__global__ __launch_bounds__(256) void k_gather2(const int* __restrict__ csr_src,
                                                 const int* __restrict__ base,
                                                 const int* __restrict__ cnt,
                                                 const float* __restrict__ dinv,
                                                 const uint2* __restrict__ g2b,   // [N][4]
                                                 const float* __restrict__ b2,
                                                 float* __restrict__ out) {
    int tid  = threadIdx.x;
    int lane = tid & 63;
    int grp  = lane >> 2;                    // 0..15
    int l4   = lane & 3;
    int g0   = lane & 60;                    // group base lane
    int node = ((blockIdx.x * 256 + tid) >> 6) * 16 + grp;
    if (node >= N_NODES) return;
    int   b  = base[node];
    int   c  = cnt[node];
    float di = dinv[node];
    float4 acc = {0.f, 0.f, 0.f, 0.f};
    accb(acc, g2b[(size_t)node * 4 + l4]);             // self term

    for (int k0 = 0; k0 < c; k0 += 4) {
        int k = k0 + l4;
        int sidx = (k < c) ? csr_src[b + k] : 0;
        int nj = min(4, c - k0);
        if (nj == 4) {
            int s0 = __shfl(sidx, g0 + 0);
            int s1 = __shfl(sidx, g0 + 1);
            int s2 = __shfl(sidx, g0 + 2);
            int s3 = __shfl(sidx, g0 + 3);
            uint2 u0 = g2b[(size_t)s0 * 4 + l4];       // 4 independent 32B rows
            uint2 u1 = g2b[(size_t)s1 * 4 + l4];
            uint2 u2 = g2b[(size_t)s2 * 4 + l4];
            uint2 u3 = g2b[(size_t)s3 * 4 + l4];
            accb(acc, u0); accb(acc, u1); accb(acc, u2); accb(acc, u3);
        } else {
            for (int j = 0; j < nj; ++j)
                accb(acc, g2b[(size_t)__shfl(sidx, g0 + j) * 4 + l4]);
        }
    }
    float4 bv = ((const float4*)b2)[l4];
    float4 r  = { fmaf(di, acc.x, bv.x), fmaf(di, acc.y, bv.y),
                  fmaf(di, acc.z, bv.z), fmaf(di, acc.w, bv.w) };
    ((float4*)out)[(size_t)node * 4 + l4] = r;
}

extern "C" void kernel_launch(void* const* d_in, const int* in_sizes, int n_in,
                              void* d_out, int out_size, void* d_ws, size_t ws_size,
                              hipStream_t stream) {
    const float* x     = (const float*)d_in[0];
    const int*   edges = (const int*)d_in[1];              // int32 (harness converts)
    const float* W1    = (const float*)d_in[2];
    const float* b1    = (const float*)d_in[3];
    const float* W2    = (const float*)d_in[4];
    const float* b2    = (const float*)d_in[5];
    float*       out   = (float*)d_out;

    const int E = in_sizes[1] / 2;                         // 3,200,000

    // workspace (~32.8 MB), concurrently-live regions disjoint:
    //   [0, 14.0 MB):    pairs (build)  -> g1b (bf16 12.8 MB; live through gather1)
    //   [14.0, 17.2 MB): g2b (bf16, N*4 uint2 = 3.2 MB; written by gather1)
    //   [17.2, 31.2 MB): csr_src (NBKT*CAP ints)
    //   [31.2, ...):     nbase | ncnt | dinv | bkt_tail
    int*   pairs   = (int*)d_ws;                           // NBKT*CAP ints
    uint2* g1b     = (uint2*)d_ws;                         // N*16 uint2 (bf16 rows)
    uint2* g2b     = (uint2*)((float*)d_ws + (size_t)NBKT * CAP);
    int*   csr_src = (int*)g2b + (size_t)N_NODES * 8 + 64; // after g2b (N*4 uint2 = N*8 int)
    int*   nbase   = csr_src + (size_t)NBKT * CAP;         // N
    int*   ncnt    = nbase + N_NODES;                      // N
    float* dinv    = (float*)(ncnt + N_NODES);             // N
    int*   bkt_tail= (int*)(dinv + N_NODES);               // NBKT*16

    const int nchunk = (E + CHUNK - 1) / CHUNK;            // 391

    // CSR build (zero via async memset — capturable stream op, saves a launch)
    hipMemsetAsync(bkt_tail, 0, (size_t)NBKT * BKT_PAD * sizeof(int), stream);
    k_bfill  <<<nchunk, 512, 0, stream>>>((const int2*)edges, bkt_tail, pairs, E);
    k_bnode  <<<NBKT, 1024, 0, stream>>>(pairs, bkt_tail, csr_src, nbase, ncnt, dinv);

    // layer 1 GEMM (MFMA bf16): 6250 tiles, 4 waves/block
    k_gemm1   <<<(N_NODES / 16 + 3) / 4, 256, 0, stream>>>(x, W1, dinv, g1b);

    // fused: gather1 + bias + relu + GEMM2 -> g2b
    k_gather1 <<<6250, 256, 0, stream>>>(csr_src, nbase, ncnt, dinv, g1b, b1, W2, g2b);

    // gather layer 2 -> out
    k_gather2 <<<1563, 256, 0, stream>>>(csr_src, nbase, ncnt, dinv, g2b, b2, out);
}

// Round 20
// 143.978 us; speedup vs baseline: 1.4587x; 1.0076x over previous
//
#include <hip/hip_runtime.h>

#define N_NODES 100000
#define F_IN    128
#define H_DIM   64
#define C_DIM   16
#define NBKT    391            // buckets of 256 nodes (dst>>8)
#define CHUNK   8192           // edges per bfill block
#define CAP     8960           // per-bucket csr capacity (lambda=8192, +8.5 sigma)
#define MAXCH   400            // >= nch = ceil(E/CHUNK) = 391

typedef __attribute__((ext_vector_type(8))) short bf16x8;   // 8 bf16 (4 VGPRs)
typedef __attribute__((ext_vector_type(4))) float f32x4;    // MFMA accum

// f32 -> bf16 round-to-nearest-even
__device__ __forceinline__ unsigned bfr(float f) {
    unsigned u = __float_as_uint(f);
    return (u + (((u >> 16) & 1u) + 0x7FFFu)) >> 16;
}
// unpack-add: two packed bf16 pairs -> 4 f32 adds
__device__ __forceinline__ void accb(float4& a, uint2 u) {
    a.x += __uint_as_float(u.x << 16);
    a.y += __uint_as_float(u.x & 0xFFFF0000u);
    a.z += __uint_as_float(u.y << 16);
    a.w += __uint_as_float(u.y & 0xFFFF0000u);
}

// ---------- bfill v4: block-local sort + DENSE segment write (no RMW, no atomics)
// Each block sorts its CHUNK by bucket and writes it densely at blk*CHUNK,
// plus per-(block,bucket) count/base tables for bnode's run gather.
__global__ __launch_bounds__(512) void k_bfill(const int2* __restrict__ edges,
                                               int* __restrict__ pairs_flat,
                                               int* __restrict__ cnts_g,
                                               int* __restrict__ lbase_g, int E) {
    __shared__ int2 sp[CHUNK];               // 64 KB block-sorted edge staging
    __shared__ int  cnt[NBKT];
    __shared__ int  lbase[NBKT];             // block-local exclusive base
    __shared__ int  scn[512];
    int t = threadIdx.x;
    for (int i = t; i < NBKT; i += 512) cnt[i] = 0;
    __syncthreads();
    int base = blockIdx.x * CHUNK;
    int m    = min(E - base, CHUNK);         // edges in this block
    int2 ed[16];                             // static idx via unroll (rule #20)
    int  rk[16];                             // rank within (block, bucket)
    #pragma unroll
    for (int i = 0; i < 16; ++i) {
        int e = i * 512 + t;
        if (e < m) {
            ed[i] = edges[base + e];
            rk[i] = atomicAdd(&cnt[ed[i].y >> 8], 1);
        }
    }
    __syncthreads();
    scn[t] = (t < NBKT) ? cnt[t] : 0;
    __syncthreads();
    #pragma unroll
    for (int off = 1; off < 512; off <<= 1) {
        int v = (t >= off) ? scn[t - off] : 0;
        __syncthreads();
        scn[t] += v;
        __syncthreads();
    }
    for (int b = t; b < NBKT; b += 512) {
        int c = cnt[b];
        int lb = scn[b] - c;                 // exclusive
        lbase[b] = lb;
        cnts_g [blockIdx.x * NBKT + b] = c;  // dense table writes (coalesced)
        lbase_g[blockIdx.x * NBKT + b] = lb;
    }
    __syncthreads();
    // block-local counting sort into LDS
    #pragma unroll
    for (int i = 0; i < 16; ++i) {
        int e = i * 512 + t;
        if (e < m) sp[lbase[ed[i].y >> 8] + rk[i]] = ed[i];
    }
    __syncthreads();
    // DENSE writeout: contiguous, aligned, full lines only
    #pragma unroll
    for (int i = 0; i < 16; ++i) {
        int idx = i * 512 + t;
        if (idx < m) {
            int2 p = sp[idx];
            pairs_flat[base + idx] = (p.x << 8) | (p.y & 255);
        }
    }
}

// ---------- bnode v2: gather bucket runs from dense segments, node-sort ----------
// block = bucket b. Copies its ~391 runs into LDS (scattered READS, no RMW),
// then hist -> scan -> node-order scatter -> dense csr write. Outputs unchanged.
__global__ __launch_bounds__(1024) void k_bnode(const int* __restrict__ pairs_flat,
                                                const int* __restrict__ cnts_g,
                                                const int* __restrict__ lbase_g,
                                                int* __restrict__ csr_src,
                                                int* __restrict__ node_base,
                                                int* __restrict__ node_cnt,
                                                float* __restrict__ dinv, int nch) {
    __shared__ int spairs[CAP];              // 35 KB staged bucket pairs
    __shared__ int sc[CAP];                  // 35 KB node-sorted csr image
    __shared__ int roff[MAXCH + 1];          // run offsets within bucket
    __shared__ int rlb[MAXCH];               // run local base within segment
    __shared__ int cnt[256];
    __shared__ int row[256];
    __shared__ int wsum[4];
    __shared__ int scn[512];
    int b = blockIdx.x;
    int t = threadIdx.x;
    if (t < 256) cnt[t] = 0;
    // load this bucket's run table (column b)
    for (int i = t; i < nch; i += 1024) {
        roff[i] = cnts_g [i * NBKT + b];     // temporarily counts
        rlb[i]  = lbase_g[i * NBKT + b];
    }
    __syncthreads();
    // exclusive scan of run counts (ladder over 512 slots, 9 rounds)
    if (t < 512) scn[t] = (t < nch) ? roff[t] : 0;
    __syncthreads();
    #pragma unroll
    for (int off = 1; off < 512; off <<= 1) {
        int v = 0;
        if (t < 512 && t >= off) v = scn[t - off];
        __syncthreads();
        if (t < 512) scn[t] += v;
        __syncthreads();
    }
    if (t < nch) roff[t] = scn[t] - ((t < nch) ? cnts_g[t * NBKT + b] : 0);
    if (t == 0) roff[nch] = scn[nch - 1];    // total m
    __syncthreads();
    int m = min(roff[nch], CAP);
    // flat copy: spairs[e] = run element, blk found by binary search in roff
    for (int e = t; e < m; e += 1024) {
        int lo = 0, hi = nch - 1;
        while (lo < hi) {                    // ~9 LDS probes
            int mid = (lo + hi + 1) >> 1;
            if (roff[mid] <= e) lo = mid; else hi = mid - 1;
        }
        int p = pairs_flat[lo * CHUNK + rlb[lo] + (e - roff[lo])];
        spairs[e] = p;
        atomicAdd(&cnt[p & 255], 1);         // hist during copy
    }
    __syncthreads();
    if (t < 256) {
        int c = cnt[t];
        int lane = t & 63, wv = t >> 6;
        int v = c;
        #pragma unroll
        for (int off = 1; off < 64; off <<= 1) {
            int u = __shfl_up(v, off);
            if (lane >= off) v += u;
        }
        if (lane == 63) wsum[wv] = v;
        __syncthreads();
        int woff = 0;
        #pragma unroll
        for (int w = 0; w < 4; ++w) woff += (w < wv) ? wsum[w] : 0;
        int incl = v + woff;                 // inclusive over 256
        row[t] = incl - c;                   // local exclusive base
        int node = b * 256 + t;
        if (node < N_NODES) {
            node_base[node] = b * CAP + incl - c;
            node_cnt[node]  = c;
            dinv[node]      = rsqrtf((float)(c + 1));   // deg = cnt+1 (self loop)
        }
    } else {
        __syncthreads();                     // match the scan's inner barrier
    }
    __syncthreads();
    for (int e = t; e < m; e += 1024) {
        int p   = spairs[e];                 // LDS read
        int pos = atomicAdd(&row[p & 255], 1);
        sc[pos] = ((unsigned)p) >> 8;
    }
    __syncthreads();
    for (int e = t; e < m; e += 1024)
        csr_src[b * CAP + e] = sc[e];        // coalesced copy-out
}

// ---------- GEMM1 (MFMA bf16): wave = 16 rows x 64 cols, K=128 ----------
__global__ __launch_bounds__(256) void k_gemm1(const float* __restrict__ x,
                                               const float* __restrict__ W1,
                                               const float* __restrict__ dinv,
                                               uint2* __restrict__ g1b) {
    __shared__ short wt[64][132];            // W1^T bf16, +4 pad
    int tid = threadIdx.x;
    {
        int n  = tid & 63;
        int k0 = (tid >> 6) * 32;
        #pragma unroll 8
        for (int k = 0; k < 32; ++k)
            wt[n][k0 + k] = (short)bfr(W1[(size_t)(k0 + k) * H_DIM + n]);
    }
    __syncthreads();

    int wave = tid >> 6, lane = tid & 63;
    int tile = blockIdx.x * 4 + wave;        // 16-row tile id
    bool valid = tile < N_NODES / 16;        // 6250 tiles exactly
    int row0 = (valid ? tile : 0) * 16;
    int l15  = lane & 15;
    int kg   = lane >> 4;                    // 0..3 (k-group of 8)
    const float* xrow = x + (size_t)(row0 + l15) * F_IN;

    f32x4 ac0 = {0.f,0.f,0.f,0.f}, ac1 = ac0, ac2 = ac0, ac3 = ac0;
    #pragma unroll
    for (int ks = 0; ks < 4; ++ks) {         // K = 128 = 4 x 32
        int kb = ks * 32 + kg * 8;
        float4 p0 = *(const float4*)(xrow + kb);
        float4 p1 = *(const float4*)(xrow + kb + 4);
        bf16x8 a;
        a[0] = (short)bfr(p0.x); a[1] = (short)bfr(p0.y);
        a[2] = (short)bfr(p0.z); a[3] = (short)bfr(p0.w);
        a[4] = (short)bfr(p1.x); a[5] = (short)bfr(p1.y);
        a[6] = (short)bfr(p1.z); a[7] = (short)bfr(p1.w);
        bf16x8 b0 = *(const bf16x8*)&wt[l15     ][kb];
        bf16x8 b1 = *(const bf16x8*)&wt[l15 + 16][kb];
        bf16x8 b2 = *(const bf16x8*)&wt[l15 + 32][kb];
        bf16x8 b3 = *(const bf16x8*)&wt[l15 + 48][kb];
        ac0 = __builtin_amdgcn_mfma_f32_16x16x32_bf16(a, b0, ac0, 0, 0, 0);
        ac1 = __builtin_amdgcn_mfma_f32_16x16x32_bf16(a, b1, ac1, 0, 0, 0);
        ac2 = __builtin_amdgcn_mfma_f32_16x16x32_bf16(a, b2, ac2, 0, 0, 0);
        ac3 = __builtin_amdgcn_mfma_f32_16x16x32_bf16(a, b3, ac3, 0, 0, 0);
    }
    if (!valid) return;

    int rbase = row0 + kg * 4;               // this lane's 4 output rows
    #pragma unroll
    for (int r = 0; r < 4; ++r) {
        float di = dinv[rbase + r];
        size_t gro = (size_t)(rbase + r) * 16;
        #pragma unroll
        for (int ct = 0; ct < 4; ++ct) {
            float v = ((ct == 0) ? ac0[r] : (ct == 1) ? ac1[r] :
                       (ct == 2) ? ac2[r] : ac3[r]) * di;
            float v1 = __shfl_down(v, 1);
            float v2 = __shfl_down(v, 2);
            float v3 = __shfl_down(v, 3);
            if ((l15 & 3) == 0) {
                uint2 pk;
                pk.x = bfr(v)  | (bfr(v1) << 16);
                pk.y = bfr(v2) | (bfr(v3) << 16);
                g1b[gro + ct * 4 + (l15 >> 2)] = pk;
            }
        }
    }
}

// ---------- fused gather1 + bias + relu + GEMM2 ----------
__global__ __launch_bounds__(256) void k_gather1(const int* __restrict__ csr_src,
                                                 const int* __restrict__ base,
                                                 const int* __restrict__ cnt,
                                                 const float* __restrict__ dinv,
                                                 const uint2* __restrict__ g1b,  // [N][16]
                                                 const float* __restrict__ b1,
                                                 const float* __restrict__ W2,   // [64][16]
                                                 uint2* __restrict__ g2b) {      // [N][4]
    __shared__ float  w2t[16 * 68];          // W2^T, rows padded to 68 floats
    __shared__ float4 ysh[4][68];            // per-wave y staging, 17-f4 group stride
    int tid = threadIdx.x;
    #pragma unroll
    for (int i = 0; i < 4; ++i) {
        int idx = i * 256 + tid;             // idx = f*16 + j
        w2t[(idx & 15) * 68 + (idx >> 4)] = W2[idx];
    }
    __syncthreads();

    int lane = tid & 63;
    int wv   = tid >> 6;                     // wave in block
    int grp  = lane >> 4;                    // 0..3
    int l16  = lane & 15;
    int g0   = lane & 48;                    // group base lane (absolute in wave)
    int node = ((blockIdx.x * 256 + tid) >> 6) * 4 + grp;   // exact: 25000 waves * 4
    int   b  = base[node];
    int   c  = cnt[node];
    float di = dinv[node];
    float4 acc = {0.f, 0.f, 0.f, 0.f};
    accb(acc, g1b[(size_t)node * 16 + l16]);           // self term

    for (int k0 = 0; k0 < c; k0 += 16) {
        int k = k0 + l16;
        int sidx = (k < c) ? csr_src[b + k] : 0;       // group-coalesced stage
        int nj = min(16, c - k0);
        int j = 0;
        for (; j + 4 <= nj; j += 4) {
            int s0 = __shfl(sidx, g0 + j + 0);
            int s1 = __shfl(sidx, g0 + j + 1);
            int s2 = __shfl(sidx, g0 + j + 2);
            int s3 = __shfl(sidx, g0 + j + 3);
            uint2 u0 = g1b[(size_t)s0 * 16 + l16];     // 4 independent 128B rows
            uint2 u1 = g1b[(size_t)s1 * 16 + l16];
            uint2 u2 = g1b[(size_t)s2 * 16 + l16];
            uint2 u3 = g1b[(size_t)s3 * 16 + l16];
            accb(acc, u0); accb(acc, u1); accb(acc, u2); accb(acc, u3);
        }
        for (; j < nj; ++j) {
            accb(acc, g1b[(size_t)__shfl(sidx, g0 + j) * 16 + l16]);
        }
    }

    // epilogue: y = di*relu(b1 + di*acc), transpose via LDS, y @ W2 -> g2b
    float4 bv = ((const float4*)b1)[l16];
    float4 y;
    y.x = fmaxf(fmaf(di, acc.x, bv.x), 0.f) * di;
    y.y = fmaxf(fmaf(di, acc.y, bv.y), 0.f) * di;
    y.z = fmaxf(fmaf(di, acc.z, bv.z), 0.f) * di;
    y.w = fmaxf(fmaf(di, acc.w, bv.w), 0.f) * di;
    ysh[wv][grp * 17 + l16] = y;             // wave-internal, DS-pipe ordered

    float o = 0.f;                           // this lane's output column j = l16
    #pragma unroll
    for (int f4 = 0; f4 < 16; ++f4) {
        float4 yv = ysh[wv][grp * 17 + f4];            // broadcast within group
        const float4* wr = (const float4*)&w2t[l16 * 68 + f4 * 4];
        float4 wv4 = *wr;
        o = fmaf(yv.x, wv4.x, o);
        o = fmaf(yv.y, wv4.y, o);
        o = fmaf(yv.z, wv4.z, o);
        o = fmaf(yv.w, wv4.w, o);
    }
    float o1 = __shfl_down(o, 1);
    float o2 = __shfl_down(o, 2);
    float o3 = __shfl_down(o, 3);
    if ((l16 & 3) == 0) {
        uint2 pk;
        pk.x = bfr(o)  | (bfr(o1) << 16);
        pk.y = bfr(o2) | (bfr(o3) << 16);
        g2b[(size_t)node * 4 + (l16 >> 2)] = pk;
    }
}

// ---------- gather layer 2: 4-lane group per node (16 nodes/wave), bf16 rows ----------
__global__ __launch_bounds__(256) void k_gather2(const int* __restrict__ csr_src,
                                                 const int* __restrict__ base,
                                                 const int* __restrict__ cnt,
                                                 const float* __restrict__ dinv,
                                                 const uint2* __restrict__ g2b,   // [N][4]
                                                 const float* __restrict__ b2,
                                                 float* __restrict__ out) {
    int tid  = threadIdx.x;
    int lane = tid & 63;
    int grp  = lane >> 2;                    // 0..15
    int l4   = lane & 3;
    int g0   = lane & 60;                    // group base lane
    int node = ((blockIdx.x * 256 + tid) >> 6) * 16 + grp;
    if (node >= N_NODES) return;
    int   b  = base[node];
    int   c  = cnt[node];
    float di = dinv[node];
    float4 acc = {0.f, 0.f, 0.f, 0.f};
    accb(acc, g2b[(size_t)node * 4 + l4]);             // self term

    for (int k0 = 0; k0 < c; k0 += 4) {
        int k = k0 + l4;
        int sidx = (k < c) ? csr_src[b + k] : 0;
        int nj = min(4, c - k0);
        if (nj == 4) {
            int s0 = __shfl(sidx, g0 + 0);
            int s1 = __shfl(sidx, g0 + 1);
            int s2 = __shfl(sidx, g0 + 2);
            int s3 = __shfl(sidx, g0 + 3);
            uint2 u0 = g2b[(size_t)s0 * 4 + l4];       // 4 independent 32B rows
            uint2 u1 = g2b[(size_t)s1 * 4 + l4];
            uint2 u2 = g2b[(size_t)s2 * 4 + l4];
            uint2 u3 = g2b[(size_t)s3 * 4 + l4];
            accb(acc, u0); accb(acc, u1); accb(acc, u2); accb(acc, u3);
        } else {
            for (int j = 0; j < nj; ++j)
                accb(acc, g2b[(size_t)__shfl(sidx, g0 + j) * 4 + l4]);
        }
    }
    float4 bv = ((const float4*)b2)[l4];
    float4 r  = { fmaf(di, acc.x, bv.x), fmaf(di, acc.y, bv.y),
                  fmaf(di, acc.z, bv.z), fmaf(di, acc.w, bv.w) };
    ((float4*)out)[(size_t)node * 4 + l4] = r;
}

extern "C" void kernel_launch(void* const* d_in, const int* in_sizes, int n_in,
                              void* d_out, int out_size, void* d_ws, size_t ws_size,
                              hipStream_t stream) {
    const float* x     = (const float*)d_in[0];
    const int*   edges = (const int*)d_in[1];              // int32 (harness converts)
    const float* W1    = (const float*)d_in[2];
    const float* b1    = (const float*)d_in[3];
    const float* W2    = (const float*)d_in[4];
    const float* b2    = (const float*)d_in[5];
    float*       out   = (float*)d_out;

    const int E   = in_sizes[1] / 2;                       // 3,200,000
    const int nch = (E + CHUNK - 1) / CHUNK;               // 391

    // workspace (~34 MB), concurrently-live regions disjoint:
    //   [A: 14.0 MB):  pairs_flat (12.8 MB, build) -> g1b (bf16 12.8 MB)
    //   [B: 3.2 MB):   g2b (N*4 uint2)
    //   [C: 14.0 MB):  csr_src (NBKT*CAP ints)
    //   [D]:           nbase | ncnt | dinv | cnts_g | lbase_g (~2.4 MB)
    int*   pairs_flat = (int*)d_ws;
    uint2* g1b     = (uint2*)d_ws;
    uint2* g2b     = (uint2*)((float*)d_ws + (size_t)NBKT * CAP);
    int*   csr_src = (int*)g2b + (size_t)N_NODES * 8 + 64;
    int*   nbase   = csr_src + (size_t)NBKT * CAP;         // N
    int*   ncnt    = nbase + N_NODES;                      // N
    float* dinv    = (float*)(ncnt + N_NODES);             // N
    int*   cnts_g  = (int*)(dinv + N_NODES);               // nch*NBKT
    int*   lbase_g = cnts_g + (size_t)nch * NBKT;          // nch*NBKT

    // CSR build: dense-segment sort (no atomics, no init) + run-merging node sort
    k_bfill <<<nch, 512, 0, stream>>>((const int2*)edges, pairs_flat,
                                      cnts_g, lbase_g, E);
    k_bnode <<<NBKT, 1024, 0, stream>>>(pairs_flat, cnts_g, lbase_g, csr_src,
                                        nbase, ncnt, dinv, nch);

    // layer 1 GEMM (MFMA bf16): 6250 tiles, 4 waves/block
    k_gemm1   <<<(N_NODES / 16 + 3) / 4, 256, 0, stream>>>(x, W1, dinv, g1b);

    // fused: gather1 + bias + relu + GEMM2 -> g2b
    k_gather1 <<<6250, 256, 0, stream>>>(csr_src, nbase, ncnt, dinv, g1b, b1, W2, g2b);

    // gather layer 2 -> out
    k_gather2 <<<1563, 256, 0, stream>>>(csr_src, nbase, ncnt, dinv, g2b, b2, out);
}

// Round 21
// 138.731 us; speedup vs baseline: 1.5139x; 1.0378x over previous
//
#include <hip/hip_runtime.h>

#define N_NODES 100000
#define F_IN    128
#define H_DIM   64
#define C_DIM   16
#define NBKT    391            // buckets of 256 nodes (dst>>8)
#define CHUNK   8192           // edges per bfill block
#define CAP     8960           // per-bucket csr capacity (lambda=8192, +8.5 sigma)
#define MAXCH   400            // >= nch = ceil(E/CHUNK) = 391

typedef __attribute__((ext_vector_type(8))) short bf16x8;   // 8 bf16 (4 VGPRs)
typedef __attribute__((ext_vector_type(4))) float f32x4;    // MFMA accum

// f32 -> bf16 round-to-nearest-even
__device__ __forceinline__ unsigned bfr(float f) {
    unsigned u = __float_as_uint(f);
    return (u + (((u >> 16) & 1u) + 0x7FFFu)) >> 16;
}
// unpack-add: two packed bf16 pairs -> 4 f32 adds
__device__ __forceinline__ void accb(float4& a, uint2 u) {
    a.x += __uint_as_float(u.x << 16);
    a.y += __uint_as_float(u.x & 0xFFFF0000u);
    a.z += __uint_as_float(u.y << 16);
    a.w += __uint_as_float(u.y & 0xFFFF0000u);
}

// ---------- bfill v4: block-local sort + DENSE segment write (no RMW, no atomics)
__global__ __launch_bounds__(512) void k_bfill(const int2* __restrict__ edges,
                                               int* __restrict__ pairs_flat,
                                               int* __restrict__ cnts_g,
                                               int* __restrict__ lbase_g, int E) {
    __shared__ int2 sp[CHUNK];               // 64 KB block-sorted edge staging
    __shared__ int  cnt[NBKT];
    __shared__ int  lbase[NBKT];             // block-local exclusive base
    __shared__ int  scn[512];
    int t = threadIdx.x;
    for (int i = t; i < NBKT; i += 512) cnt[i] = 0;
    __syncthreads();
    int base = blockIdx.x * CHUNK;
    int m    = min(E - base, CHUNK);         // edges in this block
    int2 ed[16];                             // static idx via unroll (rule #20)
    int  rk[16];                             // rank within (block, bucket)
    #pragma unroll
    for (int i = 0; i < 16; ++i) {
        int e = i * 512 + t;
        if (e < m) {
            ed[i] = edges[base + e];
            rk[i] = atomicAdd(&cnt[ed[i].y >> 8], 1);
        }
    }
    __syncthreads();
    scn[t] = (t < NBKT) ? cnt[t] : 0;
    __syncthreads();
    #pragma unroll
    for (int off = 1; off < 512; off <<= 1) {
        int v = (t >= off) ? scn[t - off] : 0;
        __syncthreads();
        scn[t] += v;
        __syncthreads();
    }
    for (int b = t; b < NBKT; b += 512) {
        int c = cnt[b];
        int lb = scn[b] - c;                 // exclusive
        lbase[b] = lb;
        cnts_g [blockIdx.x * NBKT + b] = c;  // dense table writes (coalesced)
        lbase_g[blockIdx.x * NBKT + b] = lb;
    }
    __syncthreads();
    #pragma unroll
    for (int i = 0; i < 16; ++i) {
        int e = i * 512 + t;
        if (e < m) sp[lbase[ed[i].y >> 8] + rk[i]] = ed[i];
    }
    __syncthreads();
    #pragma unroll
    for (int i = 0; i < 16; ++i) {
        int idx = i * 512 + t;
        if (idx < m) {
            int2 p = sp[idx];
            pairs_flat[base + idx] = (p.x << 8) | (p.y & 255);
        }
    }
}

// ---------- bnode v3: run-per-group copy (no binary search) ----------
// block = bucket b. 64 groups of 16 lanes; group g copies runs g, g+64, ...
// Each run is a contiguous ~21-int slice of a dense segment -> coalesced reads.
__global__ __launch_bounds__(1024) void k_bnode(const int* __restrict__ pairs_flat,
                                                const int* __restrict__ cnts_g,
                                                const int* __restrict__ lbase_g,
                                                int* __restrict__ csr_src,
                                                int* __restrict__ node_base,
                                                int* __restrict__ node_cnt,
                                                float* __restrict__ dinv, int nch) {
    __shared__ int spairs[CAP];              // 35 KB staged bucket pairs
    __shared__ int sc[CAP];                  // 35 KB node-sorted csr image
    __shared__ int rcnt[MAXCH];              // run counts
    __shared__ int rlb[MAXCH];               // run local base within segment
    __shared__ int roff[MAXCH];              // run exclusive offset within bucket
    __shared__ int scn[512];
    __shared__ int cnt[256];
    __shared__ int row[256];
    __shared__ int wsum[4];
    __shared__ int mtot;
    int b = blockIdx.x;
    int t = threadIdx.x;
    if (t < 256) cnt[t] = 0;
    for (int i = t; i < nch; i += 1024) {    // column b of the tables
        rcnt[i] = cnts_g [i * NBKT + b];
        rlb[i]  = lbase_g[i * NBKT + b];
    }
    __syncthreads();
    if (t < 512) scn[t] = (t < nch) ? rcnt[t] : 0;
    __syncthreads();
    #pragma unroll
    for (int off = 1; off < 512; off <<= 1) {
        int v = 0;
        if (t < 512 && t >= off) v = scn[t - off];
        __syncthreads();
        if (t < 512) scn[t] += v;
        __syncthreads();
    }
    if (t < nch) roff[t] = scn[t] - rcnt[t];
    if (t == 0) mtot = scn[nch - 1];
    __syncthreads();
    int m = min(mtot, CAP);
    // copy: group g -> runs g, g+64, ... ; lanes stride the run (coalesced)
    int grp = t >> 4, l16 = t & 15;
    for (int r = grp; r < nch; r += 64) {
        int c  = rcnt[r];
        int ro = roff[r];
        int rb = r * CHUNK + rlb[r];
        for (int j = l16; j < c; j += 16) {
            int pos = ro + j;
            if (pos < CAP) {
                int p = pairs_flat[rb + j];
                spairs[pos] = p;
                atomicAdd(&cnt[p & 255], 1); // hist during copy
            }
        }
    }
    __syncthreads();
    if (t < 256) {
        int c = cnt[t];
        int lane = t & 63, wv = t >> 6;
        int v = c;
        #pragma unroll
        for (int off = 1; off < 64; off <<= 1) {
            int u = __shfl_up(v, off);
            if (lane >= off) v += u;
        }
        if (lane == 63) wsum[wv] = v;
        __syncthreads();
        int woff = 0;
        #pragma unroll
        for (int w = 0; w < 4; ++w) woff += (w < wv) ? wsum[w] : 0;
        int incl = v + woff;                 // inclusive over 256
        row[t] = incl - c;                   // local exclusive base
        int node = b * 256 + t;
        if (node < N_NODES) {
            node_base[node] = b * CAP + incl - c;
            node_cnt[node]  = c;
            dinv[node]      = rsqrtf((float)(c + 1));   // deg = cnt+1 (self loop)
        }
    } else {
        __syncthreads();                     // match the scan's inner barrier
    }
    __syncthreads();
    for (int e = t; e < m; e += 1024) {
        int p   = spairs[e];                 // LDS read
        int pos = atomicAdd(&row[p & 255], 1);
        sc[pos] = ((unsigned)p) >> 8;
    }
    __syncthreads();
    for (int e = t; e < m; e += 1024)
        csr_src[b * CAP + e] = sc[e];        // coalesced copy-out
}

// ---------- GEMM1 (MFMA bf16): wave = 16 rows x 64 cols, K=128 ----------
__global__ __launch_bounds__(256) void k_gemm1(const float* __restrict__ x,
                                               const float* __restrict__ W1,
                                               const float* __restrict__ dinv,
                                               uint2* __restrict__ g1b) {
    __shared__ short wt[64][132];            // W1^T bf16, +4 pad
    int tid = threadIdx.x;
    {
        int n  = tid & 63;
        int k0 = (tid >> 6) * 32;
        #pragma unroll 8
        for (int k = 0; k < 32; ++k)
            wt[n][k0 + k] = (short)bfr(W1[(size_t)(k0 + k) * H_DIM + n]);
    }
    __syncthreads();

    int wave = tid >> 6, lane = tid & 63;
    int tile = blockIdx.x * 4 + wave;        // 16-row tile id
    bool valid = tile < N_NODES / 16;        // 6250 tiles exactly
    int row0 = (valid ? tile : 0) * 16;
    int l15  = lane & 15;
    int kg   = lane >> 4;                    // 0..3 (k-group of 8)
    const float* xrow = x + (size_t)(row0 + l15) * F_IN;

    f32x4 ac0 = {0.f,0.f,0.f,0.f}, ac1 = ac0, ac2 = ac0, ac3 = ac0;
    #pragma unroll
    for (int ks = 0; ks < 4; ++ks) {         // K = 128 = 4 x 32
        int kb = ks * 32 + kg * 8;
        float4 p0 = *(const float4*)(xrow + kb);
        float4 p1 = *(const float4*)(xrow + kb + 4);
        bf16x8 a;
        a[0] = (short)bfr(p0.x); a[1] = (short)bfr(p0.y);
        a[2] = (short)bfr(p0.z); a[3] = (short)bfr(p0.w);
        a[4] = (short)bfr(p1.x); a[5] = (short)bfr(p1.y);
        a[6] = (short)bfr(p1.z); a[7] = (short)bfr(p1.w);
        bf16x8 b0 = *(const bf16x8*)&wt[l15     ][kb];
        bf16x8 b1 = *(const bf16x8*)&wt[l15 + 16][kb];
        bf16x8 b2 = *(const bf16x8*)&wt[l15 + 32][kb];
        bf16x8 b3 = *(const bf16x8*)&wt[l15 + 48][kb];
        ac0 = __builtin_amdgcn_mfma_f32_16x16x32_bf16(a, b0, ac0, 0, 0, 0);
        ac1 = __builtin_amdgcn_mfma_f32_16x16x32_bf16(a, b1, ac1, 0, 0, 0);
        ac2 = __builtin_amdgcn_mfma_f32_16x16x32_bf16(a, b2, ac2, 0, 0, 0);
        ac3 = __builtin_amdgcn_mfma_f32_16x16x32_bf16(a, b3, ac3, 0, 0, 0);
    }
    if (!valid) return;

    int rbase = row0 + kg * 4;               // this lane's 4 output rows
    #pragma unroll
    for (int r = 0; r < 4; ++r) {
        float di = dinv[rbase + r];
        size_t gro = (size_t)(rbase + r) * 16;
        #pragma unroll
        for (int ct = 0; ct < 4; ++ct) {
            float v = ((ct == 0) ? ac0[r] : (ct == 1) ? ac1[r] :
                       (ct == 2) ? ac2[r] : ac3[r]) * di;
            float v1 = __shfl_down(v, 1);
            float v2 = __shfl_down(v, 2);
            float v3 = __shfl_down(v, 3);
            if ((l15 & 3) == 0) {
                uint2 pk;
                pk.x = bfr(v)  | (bfr(v1) << 16);
                pk.y = bfr(v2) | (bfr(v3) << 16);
                g1b[gro + ct * 4 + (l15 >> 2)] = pk;
            }
        }
    }
}

// ---------- fused gather1 + bias + relu + GEMM2 ----------
__global__ __launch_bounds__(256) void k_gather1(const int* __restrict__ csr_src,
                                                 const int* __restrict__ base,
                                                 const int* __restrict__ cnt,
                                                 const float* __restrict__ dinv,
                                                 const uint2* __restrict__ g1b,  // [N][16]
                                                 const float* __restrict__ b1,
                                                 const float* __restrict__ W2,   // [64][16]
                                                 uint2* __restrict__ g2b) {      // [N][4]
    __shared__ float  w2t[16 * 68];          // W2^T, rows padded to 68 floats
    __shared__ float4 ysh[4][68];            // per-wave y staging, 17-f4 group stride
    int tid = threadIdx.x;
    #pragma unroll
    for (int i = 0; i < 4; ++i) {
        int idx = i * 256 + tid;             // idx = f*16 + j
        w2t[(idx & 15) * 68 + (idx >> 4)] = W2[idx];
    }
    __syncthreads();

    int lane = tid & 63;
    int wv   = tid >> 6;                     // wave in block
    int grp  = lane >> 4;                    // 0..3
    int l16  = lane & 15;
    int g0   = lane & 48;                    // group base lane (absolute in wave)
    int node = ((blockIdx.x * 256 + tid) >> 6) * 4 + grp;   // exact: 25000 waves * 4
    int   b  = base[node];
    int   c  = cnt[node];
    float di = dinv[node];
    float4 acc = {0.f, 0.f, 0.f, 0.f};
    accb(acc, g1b[(size_t)node * 16 + l16]);           // self term

    for (int k0 = 0; k0 < c; k0 += 16) {
        int k = k0 + l16;
        int sidx = (k < c) ? csr_src[b + k] : 0;       // group-coalesced stage
        int nj = min(16, c - k0);
        int j = 0;
        for (; j + 4 <= nj; j += 4) {
            int s0 = __shfl(sidx, g0 + j + 0);
            int s1 = __shfl(sidx, g0 + j + 1);
            int s2 = __shfl(sidx, g0 + j + 2);
            int s3 = __shfl(sidx, g0 + j + 3);
            uint2 u0 = g1b[(size_t)s0 * 16 + l16];     // 4 independent 128B rows
            uint2 u1 = g1b[(size_t)s1 * 16 + l16];
            uint2 u2 = g1b[(size_t)s2 * 16 + l16];
            uint2 u3 = g1b[(size_t)s3 * 16 + l16];
            accb(acc, u0); accb(acc, u1); accb(acc, u2); accb(acc, u3);
        }
        for (; j < nj; ++j) {
            accb(acc, g1b[(size_t)__shfl(sidx, g0 + j) * 16 + l16]);
        }
    }

    // epilogue: y = di*relu(b1 + di*acc), transpose via LDS, y @ W2 -> g2b
    float4 bv = ((const float4*)b1)[l16];
    float4 y;
    y.x = fmaxf(fmaf(di, acc.x, bv.x), 0.f) * di;
    y.y = fmaxf(fmaf(di, acc.y, bv.y), 0.f) * di;
    y.z = fmaxf(fmaf(di, acc.z, bv.z), 0.f) * di;
    y.w = fmaxf(fmaf(di, acc.w, bv.w), 0.f) * di;
    ysh[wv][grp * 17 + l16] = y;             // wave-internal, DS-pipe ordered

    float o = 0.f;                           // this lane's output column j = l16
    #pragma unroll
    for (int f4 = 0; f4 < 16; ++f4) {
        float4 yv = ysh[wv][grp * 17 + f4];            // broadcast within group
        const float4* wr = (const float4*)&w2t[l16 * 68 + f4 * 4];
        float4 wv4 = *wr;
        o = fmaf(yv.x, wv4.x, o);
        o = fmaf(yv.y, wv4.y, o);
        o = fmaf(yv.z, wv4.z, o);
        o = fmaf(yv.w, wv4.w, o);
    }
    float o1 = __shfl_down(o, 1);
    float o2 = __shfl_down(o, 2);
    float o3 = __shfl_down(o, 3);
    if ((l16 & 3) == 0) {
        uint2 pk;
        pk.x = bfr(o)  | (bfr(o1) << 16);
        pk.y = bfr(o2) | (bfr(o3) << 16);
        g2b[(size_t)node * 4 + (l16 >> 2)] = pk;
    }
}

// ---------- gather layer 2: 4-lane group per node (16 nodes/wave), bf16 rows ----------
__global__ __launch_bounds__(256) void k_gather2(const int* __restrict__ csr_src,
                                                 const int* __restrict__ base,
                                                 const int* __restrict__ cnt,
                                                 const float* __restrict__ dinv,
                                                 const uint2* __restrict__ g2b,   // [N][4]
                                                 const float* __restrict__ b2,
                                                 float* __restrict__ out) {
    int tid  = threadIdx.x;
    int lane = tid & 63;
    int grp  = lane >> 2;                    // 0..15
    int l4   = lane & 3;
    int g0   = lane & 60;                    // group base lane
    int node = ((blockIdx.x * 256 + tid) >> 6) * 16 + grp;
    if (node >= N_NODES) return;
    int   b  = base[node];
    int   c  = cnt[node];
    float di = dinv[node];
    float4 acc = {0.f, 0.f, 0.f, 0.f};
    accb(acc, g2b[(size_t)node * 4 + l4]);             // self term

    for (int k0 = 0; k0 < c; k0 += 4) {
        int k = k0 + l4;
        int sidx = (k < c) ? csr_src[b + k] : 0;
        int nj = min(4, c - k0);
        if (nj == 4) {
            int s0 = __shfl(sidx, g0 + 0);
            int s1 = __shfl(sidx, g0 + 1);
            int s2 = __shfl(sidx, g0 + 2);
            int s3 = __shfl(sidx, g0 + 3);
            uint2 u0 = g2b[(size_t)s0 * 4 + l4];       // 4 independent 32B rows
            uint2 u1 = g2b[(size_t)s1 * 4 + l4];
            uint2 u2 = g2b[(size_t)s2 * 4 + l4];
            uint2 u3 = g2b[(size_t)s3 * 4 + l4];
            accb(acc, u0); accb(acc, u1); accb(acc, u2); accb(acc, u3);
        } else {
            for (int j = 0; j < nj; ++j)
                accb(acc, g2b[(size_t)__shfl(sidx, g0 + j) * 4 + l4]);
        }
    }
    float4 bv = ((const float4*)b2)[l4];
    float4 r  = { fmaf(di, acc.x, bv.x), fmaf(di, acc.y, bv.y),
                  fmaf(di, acc.z, bv.z), fmaf(di, acc.w, bv.w) };
    ((float4*)out)[(size_t)node * 4 + l4] = r;
}

extern "C" void kernel_launch(void* const* d_in, const int* in_sizes, int n_in,
                              void* d_out, int out_size, void* d_ws, size_t ws_size,
                              hipStream_t stream) {
    const float* x     = (const float*)d_in[0];
    const int*   edges = (const int*)d_in[1];              // int32 (harness converts)
    const float* W1    = (const float*)d_in[2];
    const float* b1    = (const float*)d_in[3];
    const float* W2    = (const float*)d_in[4];
    const float* b2    = (const float*)d_in[5];
    float*       out   = (float*)d_out;

    const int E   = in_sizes[1] / 2;                       // 3,200,000
    const int nch = (E + CHUNK - 1) / CHUNK;               // 391

    // workspace (~34 MB), concurrently-live regions disjoint:
    //   [A: 14.0 MB):  pairs_flat (12.8 MB, build) -> g1b (bf16 12.8 MB)
    //   [B: 3.2 MB):   g2b (N*4 uint2)
    //   [C: 14.0 MB):  csr_src (NBKT*CAP ints)
    //   [D]:           nbase | ncnt | dinv | cnts_g | lbase_g (~2.4 MB)
    int*   pairs_flat = (int*)d_ws;
    uint2* g1b     = (uint2*)d_ws;
    uint2* g2b     = (uint2*)((float*)d_ws + (size_t)NBKT * CAP);
    int*   csr_src = (int*)g2b + (size_t)N_NODES * 8 + 64;
    int*   nbase   = csr_src + (size_t)NBKT * CAP;         // N
    int*   ncnt    = nbase + N_NODES;                      // N
    float* dinv    = (float*)(ncnt + N_NODES);             // N
    int*   cnts_g  = (int*)(dinv + N_NODES);               // nch*NBKT
    int*   lbase_g = cnts_g + (size_t)nch * NBKT;          // nch*NBKT

    // CSR build: dense-segment sort + run-per-group node sort (no binary search)
    k_bfill <<<nch, 512, 0, stream>>>((const int2*)edges, pairs_flat,
                                      cnts_g, lbase_g, E);
    k_bnode <<<NBKT, 1024, 0, stream>>>(pairs_flat, cnts_g, lbase_g, csr_src,
                                        nbase, ncnt, dinv, nch);

    // layer 1 GEMM (MFMA bf16): 6250 tiles, 4 waves/block
    k_gemm1   <<<(N_NODES / 16 + 3) / 4, 256, 0, stream>>>(x, W1, dinv, g1b);

    // fused: gather1 + bias + relu + GEMM2 -> g2b
    k_gather1 <<<6250, 256, 0, stream>>>(csr_src, nbase, ncnt, dinv, g1b, b1, W2, g2b);

    // gather layer 2 -> out
    k_gather2 <<<1563, 256, 0, stream>>>(csr_src, nbase, ncnt, dinv, g2b, b2, out);
}